// Round 12
// baseline (199.712 us; speedup 1.0000x reference)
//
#include <hip/hip_runtime.h>
#include <math.h>

#define NEG_INF -10000.0f
// NEG_INF * log2(e): masked scores live in exp2 domain now
#define NEG_INF_L2E -14426.950408889634f

typedef short bf16x8 __attribute__((ext_vector_type(8)));
typedef float f32x4 __attribute__((ext_vector_type(4)));
typedef unsigned u32x4 __attribute__((ext_vector_type(4)));

static constexpr int Dm = 256;   // model dim
static constexpr int Lm = 256;   // residues
static constexpr int Sm = 128;   // sequences
static constexpr int Mrows = Sm * Lm;  // 32768
static constexpr size_t HB = (size_t)Mrows * 32;  // head-plane stride (elems)

__device__ __forceinline__ ushort f2bf(float x) {
    unsigned u = __float_as_uint(x);
    unsigned r = (u + 0x7FFFu + ((u >> 16) & 1u)) >> 16;
    return (ushort)r;
}
__device__ __forceinline__ float bf2f(ushort h) {
    return __uint_as_float(((unsigned)h) << 16);
}
// packed f32x2 -> bf16x2 (RNE; bit-identical to f2bf for normals)
__device__ __forceinline__ unsigned cvtpk2(float a, float b) {
    unsigned r;
    asm("v_cvt_pk_bf16_f32 %0, %1, %2" : "=v"(r) : "v"(a), "v"(b));
    return r;
}
__device__ __forceinline__ void gload_lds16(const void* g, void* l) {
    __builtin_amdgcn_global_load_lds((__attribute__((address_space(1))) void*)g,
                                     (__attribute__((address_space(3))) void*)l,
                                     16, 0, 0);
}
__device__ __forceinline__ f32x4 mfma16(bf16x8 a, bf16x8 b, f32x4 c) {
    return __builtin_amdgcn_mfma_f32_16x16x32_bf16(a, b, c, 0, 0, 0);
}

// ---------------------------------------------------------------------------
// prep_all: one launch for LN+split (blocks [0,8192)), W hi/lo split
// (blocks [8192,8512): 5 mats x 64), mask decode (block 8512).
// ---------------------------------------------------------------------------
__global__ __launch_bounds__(256)
void prep_all(const float* __restrict__ m, const float* __restrict__ lng,
              const float* __restrict__ lnb,
              ushort* __restrict__ Ahi, ushort* __restrict__ Alo,
              const float* __restrict__ W0, const float* __restrict__ W1,
              const float* __restrict__ W2, const float* __restrict__ W3,
              const float* __restrict__ W4, ushort* __restrict__ Whi,
              ushort* __restrict__ Wlo,
              const unsigned* __restrict__ seq_raw,
              const unsigned* __restrict__ res_raw,
              float* __restrict__ qflag, float* __restrict__ kbias) {
    const int bx = blockIdx.x;
    if (bx < 8192) {
        // ---- LayerNorm + bf16 hi/lo split: one wave per row ----
        const int wid = threadIdx.x >> 6, lane = threadIdx.x & 63;
        const int row = (bx << 2) + wid;
        const float4 a = ((const float4*)(m + (size_t)row * Dm))[lane];
        float s  = a.x + a.y + a.z + a.w;
        float ss = a.x*a.x + a.y*a.y + a.z*a.z + a.w*a.w;
        #pragma unroll
        for (int off = 32; off > 0; off >>= 1) {
            s  += __shfl_xor(s, off);
            ss += __shfl_xor(ss, off);
        }
        const float mu = s * (1.0f / 256.0f);
        const float rs = rsqrtf(ss * (1.0f / 256.0f) - mu * mu + 1e-5f);
        const float4 g = ((const float4*)lng)[lane];
        const float4 b = ((const float4*)lnb)[lane];
        const float x0 = (a.x - mu) * rs * g.x + b.x;
        const float x1 = (a.y - mu) * rs * g.y + b.y;
        const float x2 = (a.z - mu) * rs * g.z + b.z;
        const float x3 = (a.w - mu) * rs * g.w + b.w;
        const unsigned h0 = cvtpk2(x0, x1);
        const unsigned h1 = cvtpk2(x2, x3);
        const float r0 = x0 - __uint_as_float(h0 << 16);
        const float r1 = x1 - __uint_as_float(h0 & 0xFFFF0000u);
        const float r2 = x2 - __uint_as_float(h1 << 16);
        const float r3 = x3 - __uint_as_float(h1 & 0xFFFF0000u);
        const unsigned l0 = cvtpk2(r0, r1);
        const unsigned l1 = cvtpk2(r2, r3);
        uint2 hv, lv;
        hv.x = h0; hv.y = h1;
        lv.x = l0; lv.y = l1;
        const size_t o = (size_t)row * 256 + 4 * lane;
        *(uint2*)(Ahi + o) = hv;
        *(uint2*)(Alo + o) = lv;
        return;
    }
    if (bx < 8512) {
        // ---- W hi/lo split, mats 0-3 even/odd row-permuted ----
        const int b = bx - 8192;
        const int mat = b >> 6, xb = b & 63;
        const float* Ws[5] = {W0, W1, W2, W3, W4};
        const size_t idx = ((size_t)xb * 256 + threadIdx.x) * 4;
        const float4 v = *(const float4*)(Ws[mat] + idx);
        ushort4 hi, lo;
        hi.x = f2bf(v.x); lo.x = f2bf(v.x - bf2f(hi.x));
        hi.y = f2bf(v.y); lo.y = f2bf(v.y - bf2f(hi.y));
        hi.z = f2bf(v.z); lo.z = f2bf(v.z - bf2f(hi.z));
        hi.w = f2bf(v.w); lo.w = f2bf(v.w - bf2f(hi.w));
        const int row = (int)(idx >> 8), col = (int)(idx & 255);
        int drow = row;
        if (mat < 4) {
            const int ch = row & 31;
            const int p = (ch & 1) ? 16 + (ch >> 1) : (ch >> 1);
            drow = (row & ~31) | p;
        }
        const size_t o = (size_t)mat * 65536 + (size_t)drow * 256 + col;
        *(ushort4*)(Whi + o) = hi;
        *(ushort4*)(Wlo + o) = lo;
        return;
    }
    // ---- mask decode (single block) ----
    __shared__ unsigned long long sb[4], sf[4];
    __shared__ int enc;
    const int t = threadIdx.x;
    unsigned w = 0;
    if (t < 64)        w = seq_raw[t];
    else if (t < 128)  w = res_raw[t - 64];
    bool bad = (w != 0u) && (w != 1u) && (w != 0x3f800000u);
    bool isf = (w == 0x3f800000u);
    unsigned long long bm = __ballot(bad);
    unsigned long long fm = __ballot(isf);
    const int wid = t >> 6;
    if ((t & 63) == 0) { sb[wid] = bm; sf[wid] = fm; }
    __syncthreads();
    if (t == 0) {
        unsigned long long B = sb[0] | sb[1];
        unsigned long long F = sf[0] | sf[1];
        enc = B ? 2 : (F ? 1 : 0);
    }
    __syncthreads();
    const int e = enc;
    int sv, rv;
    if (e == 2) {
        const unsigned char* sp = (const unsigned char*)seq_raw;
        const unsigned char* rp = (const unsigned char*)res_raw;
        sv = sp[t]; rv = rp[t];
    } else if (e == 1) {
        sv = (((const float*)seq_raw)[t] != 0.0f);
        rv = (((const float*)res_raw)[t] != 0.0f);
    } else {
        sv = (seq_raw[t] != 0u);
        rv = (res_raw[t] != 0u);
    }
    qflag[t] = sv ? NEG_INF : 0.0f;
    kbias[t] = rv ? NEG_INF_L2E : 0.0f;   // pre-scaled for exp2-domain softmax
}

// ---------------------------------------------------------------------------
// Fused QKVG GEMM v6 (r8 proven version): 512-thread block, tile M=128 x
// N=256 (one matrix), per-wave 64x64, counted-vmcnt(4) dbuf pipeline, 64 KB.
// V (mat==2) stored PRE-TRANSPOSED in attn2's swizzled V^T plane layout.
// NOTE: qscale now includes log2(e) (softmax runs in exp2 domain).
// ---------------------------------------------------------------------------
__global__ __launch_bounds__(512, 4)
void qkvg_fused(const ushort* __restrict__ Ahig, const ushort* __restrict__ Alog,
                const ushort* __restrict__ Whi, const float* __restrict__ bg,
                ushort* __restrict__ qb, ushort* __restrict__ kb,
                ushort* __restrict__ vb, ushort* __restrict__ gbf,
                float qscale) {
    __shared__ __align__(16) ushort Wh[2][256 * 32];   // 2 x 16 KB
    __shared__ __align__(16) ushort Ah[2][128 * 32];   // 2 x 8 KB
    __shared__ __align__(16) ushort Al[2][128 * 32];   // 2 x 8 KB
    const int tid = threadIdx.x, lane = tid & 63, wave = tid >> 6;
    const int li = lane & 15, quad = lane >> 4;
    const int m0 = blockIdx.x << 7;         // m-tile (fastest), M=128
    const int mat = blockIdx.y;             // matrix 0..3
    const int wm = (wave >> 2) << 6;        // wave m-half: 0 / 64
    const int wn = (wave & 3) << 6;         // wave n-slice: 0/64/128/192

    const int l4 = lane >> 2, slot = lane & 3;

    f32x4 zero = {0.f, 0.f, 0.f, 0.f};
    f32x4 acc[4][4];
    #pragma unroll
    for (int i = 0; i < 4; ++i)
        #pragma unroll
        for (int j = 0; j < 4; ++j) acc[i][j] = zero;

    const ushort* Wmat = Whi + (size_t)mat * 65536;

#define STAGE(kt, buf) do {                                                    \
    _Pragma("unroll")                                                          \
    for (int j_ = 0; j_ < 2; ++j_) {                                           \
        const int wrow_ = wave * 32 + j_ * 16 + l4;                            \
        const int wsw_ = (wrow_ & 3) ^ ((wrow_ >> 2) & 3);                     \
        gload_lds16(Wmat + (size_t)wrow_ * 256 + (kt) + ((slot ^ wsw_) << 3),  \
                    &Wh[buf][wave * 1024 + j_ * 512]);                         \
    }                                                                          \
    {                                                                          \
        const int arow_ = wave * 16 + l4;                                      \
        const int asw_ = (arow_ & 3) ^ ((arow_ >> 2) & 3);                     \
        const size_t asrc_ = (size_t)(m0 + arow_) * 256 + (kt) + ((slot ^ asw_) << 3); \
        gload_lds16(Ahig + asrc_, &Ah[buf][wave * 512]);                       \
        gload_lds16(Alog + asrc_, &Al[buf][wave * 512]);                       \
    } } while (0)

#define COMPUTE(buf) do {                                                      \
    bf16x8 ah_[4], al_[4];                                                     \
    _Pragma("unroll")                                                          \
    for (int mt_ = 0; mt_ < 4; ++mt_) {                                        \
        const int r_ = wm + mt_ * 16 + li;                                     \
        const int sw_ = (r_ & 3) ^ ((r_ >> 2) & 3);                            \
        const int off_ = r_ * 32 + ((quad ^ sw_) << 3);                        \
        ah_[mt_] = *(const bf16x8*)&Ah[buf][off_];                             \
        al_[mt_] = *(const bf16x8*)&Al[buf][off_];                             \
    }                                                                          \
    _Pragma("unroll")                                                          \
    for (int nt_ = 0; nt_ < 4; ++nt_) {                                        \
        const int rn_ = wn + nt_ * 16 + li;                                    \
        const int sw_ = (rn_ & 3) ^ ((rn_ >> 2) & 3);                          \
        const bf16x8 bh_ = *(const bf16x8*)&Wh[buf][rn_ * 32 + ((quad ^ sw_) << 3)]; \
        _Pragma("unroll")                                                      \
        for (int mt_ = 0; mt_ < 4; ++mt_) {                                    \
            acc[mt_][nt_] = mfma16(ah_[mt_], bh_, acc[mt_][nt_]);              \
            acc[mt_][nt_] = mfma16(al_[mt_], bh_, acc[mt_][nt_]);              \
        }                                                                      \
    } } while (0)

    STAGE(0, 0);
    int cur = 0;
    for (int kt = 32; kt < 256; kt += 32) {
        STAGE(kt, cur ^ 1);                       // 4 loads -> in flight
        asm volatile("s_waitcnt vmcnt(4)\n\ts_barrier" ::: "memory");
        COMPUTE(cur);
        asm volatile("s_barrier" ::: "memory");   // readers done before overwrite
        cur ^= 1;
    }
    asm volatile("s_waitcnt vmcnt(0)\n\ts_barrier" ::: "memory");
    COMPUTE(cur);                                 // last tile

#undef STAGE
#undef COMPUTE

    if (mat == 2) {
        // V epilogue: store into attn2's swizzled V^T plane layout.
        const int s = m0 >> 8;                    // sequence of this 128-row tile
        const int keyOff = m0 & 255;              // 0 or 128 within the plane
        #pragma unroll
        for (int j = 0; j < 2; ++j) {
            const int hh = (wave & 3) * 2 + j;
            #pragma unroll
            for (int mt = 0; mt < 4; ++mt) {
                const int key = keyOff + wm + mt * 16 + quad * 4;  // r=0 key
                const int vkb = key >> 5, vq = (key >> 3) & 3, vj0 = key & 7;
                const int vsw = (4 * vkb + vq) & 7;
                const size_t pb = (size_t)hh * HB + (size_t)s * 8192
                                + vkb * 1024 + vq * 128 + ((li ^ vsw) << 3) + vj0;
                uint2 uE, uO;
                uE.x = cvtpk2(acc[mt][2 * j][0],     acc[mt][2 * j][1]);
                uE.y = cvtpk2(acc[mt][2 * j][2],     acc[mt][2 * j][3]);
                uO.x = cvtpk2(acc[mt][2 * j + 1][0], acc[mt][2 * j + 1][1]);
                uO.y = cvtpk2(acc[mt][2 * j + 1][2], acc[mt][2 * j + 1][3]);
                *(uint2*)&vb[pb]       = uE;
                *(uint2*)&vb[pb + 512] = uO;
            }
        }
    } else {
        ushort* outp = (mat == 0) ? qb : (mat == 1) ? kb : gbf;
        #pragma unroll
        for (int j = 0; j < 2; ++j) {
            const int hh = (wave & 3) * 2 + j;
            const int cE = hh * 32 + 2 * li;
            const float2 bg2 = *(const float2*)(bg + cE);
            #pragma unroll
            for (int mt = 0; mt < 4; ++mt) {
                #pragma unroll
                for (int r = 0; r < 4; ++r) {
                    const int row = m0 + wm + mt * 16 + quad * 4 + r;
                    float vE = acc[mt][2 * j][r];
                    float vO = acc[mt][2 * j + 1][r];
                    if (mat == 0) { vE *= qscale; vO *= qscale; }
                    if (mat == 3) {
                        vE = 1.0f / (1.0f + __expf(-(vE + bg2.x)));
                        vO = 1.0f / (1.0f + __expf(-(vO + bg2.y)));
                    }
                    const unsigned u = cvtpk2(vE, vO);
                    *(unsigned*)&outp[(size_t)hh * HB + (size_t)row * 32 + 2 * li] = u;
                }
            }
        }
    }
}

// ---------------------------------------------------------------------------
// Attention v9: exp2-domain softmax, NO max pass. Scores arrive pre-scaled
// by log2(e) (via qscale); kbias pre-scaled. Unmasked |s'| <~ 12 so exp2 is
// safe without max-norm; masked -> exp2(-14427) == 0. P and ls scale
// together so the normalized output is identical to fp32 rounding.
// Per-score VALU: 5 ops -> 2 (fma + v_exp), max pass + 2 shfl deleted.
// ---------------------------------------------------------------------------
__global__ __launch_bounds__(256, 2)
void attn2(const ushort* __restrict__ Qb, const ushort* __restrict__ Kb,
           const ushort* __restrict__ Vtb, const ushort* __restrict__ Gb,
           const float* __restrict__ qflag, const float* __restrict__ kbias,
           ushort* __restrict__ Ohi, ushort* __restrict__ Olo) {
    __shared__ __align__(16) ushort Kl[8192];   // 16 KB swizzled K
    __shared__ __align__(16) ushort Vt[8192];   // 16 KB paired/swizzled V^T
    const int h = blockIdx.x, s = blockIdx.y;
    const int tid = threadIdx.x, lane = tid & 63, wave = tid >> 6;
    const int li = lane & 15, quad = lane >> 4;
    const size_t base = (size_t)h * HB + (size_t)s * 8192;

    // --- K staging (XOR-swizzled, global_load_lds) ---
    const int srow = tid >> 2, slot = tid & 3;
    const int sw0 = (srow & 3) ^ ((srow >> 2) & 3);
    const int gk0 = (slot ^ sw0) << 3;
    #pragma unroll
    for (int i = 0; i < 4; ++i) {
        const int r = i * 64 + srow;
        gload_lds16(Kb + base + (size_t)r * 32 + gk0, &Kl[i * 2048 + wave * 512]);
    }
    // --- V^T staging: linear copy (layout pre-arranged by qkvg) ---
    #pragma unroll
    for (int i = 0; i < 4; ++i) {
        const int off = i * 2048 + wave * 512;
        gload_lds16(Vtb + base + off + (lane << 3), &Vt[off]);
    }
    __syncthreads();

    f32x4 zero = {0.f, 0.f, 0.f, 0.f};

    for (int chunk = 0; chunk < 4; ++chunk) {
        const int q0 = wave * 64 + chunk * 16;     // query base (residue)
        const bf16x8 qf = *(const bf16x8*)(Qb + base + (size_t)(q0 + li) * 32 + quad * 8);
        const float kmul = (qflag[q0 + li] != 0.0f) ? 0.0f : 1.0f;
        unsigned gpre[4];
        #pragma unroll
        for (int r = 0; r < 4; ++r)
            gpre[r] = *(const unsigned*)(Gb + base +
                          (size_t)(q0 + 4 * quad + r) * 32 + 2 * li);

        f32x4 sc[16];
        __builtin_amdgcn_s_setprio(1);
        #pragma unroll
        for (int t = 0; t < 16; ++t) {
            const int kr = (t >> 1) * 32 + ((li >> 2) << 3) + ((t & 1) << 2) + (li & 3);
            const int sw = (kr & 3) ^ ((kr >> 2) & 3);
            const bf16x8 kf = *(const bf16x8*)&Kl[kr * 32 + ((quad ^ sw) << 3)];
            sc[t] = mfma16(kf, qf, zero);
        }
        __builtin_amdgcn_s_setprio(0);
        // sc[t][r] = S'^T[key][query=li] in exp2 domain; bias + exp2 + sum.
        float ls = 0.0f;
        #pragma unroll
        for (int t = 0; t < 16; ++t) {
            const float4 kb4 = ((const float4*)kbias)[(t >> 1) * 8 + quad * 2 + (t & 1)];
            sc[t][0] = exp2f(kmul * kb4.x + sc[t][0]);
            sc[t][1] = exp2f(kmul * kb4.y + sc[t][1]);
            sc[t][2] = exp2f(kmul * kb4.z + sc[t][2]);
            sc[t][3] = exp2f(kmul * kb4.w + sc[t][3]);
            ls += sc[t][0] + sc[t][1] + sc[t][2] + sc[t][3];
        }
        ls += __shfl_xor(ls, 16);
        ls += __shfl_xor(ls, 32);
        const float inv_own = 1.0f / ls;

        f32x4 a0 = zero, a1 = zero;
        __builtin_amdgcn_s_setprio(1);
        #pragma unroll
        for (int kbk = 0; kbk < 8; ++kbk) {
            u32x4 pu;
            pu[0] = cvtpk2(sc[2 * kbk][0],     sc[2 * kbk][1]);
            pu[1] = cvtpk2(sc[2 * kbk][2],     sc[2 * kbk][3]);
            pu[2] = cvtpk2(sc[2 * kbk + 1][0], sc[2 * kbk + 1][1]);
            pu[3] = cvtpk2(sc[2 * kbk + 1][2], sc[2 * kbk + 1][3]);
            const bf16x8 pf = __builtin_bit_cast(bf16x8, pu);
            const int vsw = (4 * kbk + quad) & 7;
            const bf16x8 v0 = *(const bf16x8*)&Vt[kbk * 1024 + quad * 128 + ((li ^ vsw) << 3)];
            const bf16x8 v1 = *(const bf16x8*)&Vt[kbk * 1024 + 512 + quad * 128 + ((li ^ vsw) << 3)];
            a0 = mfma16(pf, v0, a0);
            a1 = mfma16(pf, v1, a1);
        }
        __builtin_amdgcn_s_setprio(0);
        #pragma unroll
        for (int r = 0; r < 4; ++r) {
            const float inv = __shfl(inv_own, 4 * quad + r);
            const int rowq = q0 + 4 * quad + r;
            const size_t ro = base + (size_t)rowq * 32;
            const unsigned gu = gpre[r];
            const float g0 = bf2f((ushort)(gu & 0xFFFFu));
            const float g1 = bf2f((ushort)(gu >> 16));
            const float x0 = a0[r] * inv * g0;
            const float x1 = a1[r] * inv * g1;
            const unsigned uhi = cvtpk2(x0, x1);
            const float r0 = x0 - __uint_as_float(uhi << 16);
            const float r1 = x1 - __uint_as_float(uhi & 0xFFFF0000u);
            const unsigned ulo = cvtpk2(r0, r1);
            *(unsigned*)&Ohi[ro + 2 * li] = uhi;
            *(unsigned*)&Olo[ro + 2 * li] = ulo;
        }
    }
}

// ---------------------------------------------------------------------------
// Final GEMM v3 (unchanged): 512-thread / 8-wave block, tile M=128 x N=128,
// per-wave 64x32, counted-vmcnt(4) pipeline, fp32 out + bias.
// ---------------------------------------------------------------------------
__global__ __launch_bounds__(512, 4)
void gemm_mfma(const ushort* __restrict__ Ahi, const ushort* __restrict__ Alo,
               const ushort* __restrict__ Whi, const ushort* __restrict__ Wlo,
               const float* __restrict__ bias, float* __restrict__ outp) {
    __shared__ __align__(16) ushort lds[2][16384];
    const int tid = threadIdx.x;
    const int lane = tid & 63, wave = tid >> 6;
    const int li = lane & 15, quad = lane >> 4;
    const int m0 = blockIdx.y << 7, n0 = blockIdx.x << 7;
    const int wm = (wave >> 2) << 6;        // 0 / 64
    const int wn = (wave & 3) << 5;         // 0 / 32 / 64 / 96
    const int srow = tid >> 2, slot = tid & 3;   // srow in [0,128)
    const int sw0 = (srow & 3) ^ ((srow >> 2) & 3);
    const int gk0 = (slot ^ sw0) << 3;

    f32x4 zero = {0.f, 0.f, 0.f, 0.f};
    f32x4 acc[4][2];
    #pragma unroll
    for (int i = 0; i < 4; ++i)
        #pragma unroll
        for (int j = 0; j < 2; ++j) acc[i][j] = zero;

#define GSTAGE(kt, buf) do {                                                   \
    const size_t hplane_ = (size_t)((kt) >> 5) * HB;                           \
    const size_t ao_ = hplane_ + (size_t)(m0 + srow) * 32 + gk0;               \
    const size_t wo_ = (size_t)(n0 + srow) * 256 + (kt) + gk0;                 \
    gload_lds16(Ahi + ao_, &lds[buf][wave * 512]);                             \
    gload_lds16(Alo + ao_, &lds[buf][4096 + wave * 512]);                      \
    gload_lds16(Whi + wo_, &lds[buf][8192 + wave * 512]);                      \
    gload_lds16(Wlo + wo_, &lds[buf][12288 + wave * 512]);                     \
    } while (0)

#define GCOMPUTE(buf) do {                                                     \
    bf16x8 ah_[4], al_[4], bh_[2], bl_[2];                                     \
    _Pragma("unroll")                                                          \
    for (int mt_ = 0; mt_ < 4; ++mt_) {                                        \
        const int r_ = wm + mt_ * 16 + li;                                     \
        const int sw_ = (r_ & 3) ^ ((r_ >> 2) & 3);                            \
        const int off_ = r_ * 32 + ((quad ^ sw_) << 3);                        \
        ah_[mt_] = *(const bf16x8*)&lds[buf][off_];                            \
        al_[mt_] = *(const bf16x8*)&lds[buf][4096 + off_];                     \
    }                                                                          \
    _Pragma("unroll")                                                          \
    for (int nt_ = 0; nt_ < 2; ++nt_) {                                        \
        const int r_ = wn + nt_ * 16 + li;                                     \
        const int sw_ = (r_ & 3) ^ ((r_ >> 2) & 3);                            \
        const int off_ = r_ * 32 + ((quad ^ sw_) << 3);                        \
        bh_[nt_] = *(const bf16x8*)&lds[buf][8192 + off_];                     \
        bl_[nt_] = *(const bf16x8*)&lds[buf][12288 + off_];                    \
    }                                                                          \
    _Pragma("unroll")                                                          \
    for (int mt_ = 0; mt_ < 4; ++mt_)                                          \
        _Pragma("unroll")                                                      \
        for (int nt_ = 0; nt_ < 2; ++nt_) {                                    \
            acc[mt_][nt_] = mfma16(ah_[mt_], bh_[nt_], acc[mt_][nt_]);         \
            acc[mt_][nt_] = mfma16(al_[mt_], bh_[nt_], acc[mt_][nt_]);         \
            acc[mt_][nt_] = mfma16(ah_[mt_], bl_[nt_], acc[mt_][nt_]);         \
        } } while (0)

    GSTAGE(0, 0);
    int cur = 0;
    for (int kt = 32; kt < 256; kt += 32) {
        GSTAGE(kt, cur ^ 1);                      // 4 loads in flight
        asm volatile("s_waitcnt vmcnt(4)\n\ts_barrier" ::: "memory");
        GCOMPUTE(cur);
        asm volatile("s_barrier" ::: "memory");
        cur ^= 1;
    }
    asm volatile("s_waitcnt vmcnt(0)\n\ts_barrier" ::: "memory");
    GCOMPUTE(cur);

#undef GSTAGE
#undef GCOMPUTE

    #pragma unroll
    for (int mt = 0; mt < 4; ++mt) {
        const int rowb = m0 + wm + mt * 16 + quad * 4;
        #pragma unroll
        for (int nt = 0; nt < 2; ++nt) {
            const int col = n0 + wn + nt * 16 + li;
            const float bv = bias[col];
            #pragma unroll
            for (int r = 0; r < 4; ++r) {
                const size_t o = (size_t)(rowb + r) * 256 + col;
                outp[o] = acc[mt][nt][r] + bv;
            }
        }
    }
}

// ---------------------------------------------------------------------------
// Launch. Ahi/Alo (normalized input, bf16 hi/lo) ALIAS Ohi/Olo: dead by the
// time attn2 writes them (qkvg consumed A before attn2 runs; stream-ordered).
// ---------------------------------------------------------------------------
extern "C" void kernel_launch(void* const* d_in, const int* in_sizes, int n_in,
                              void* d_out, int out_size, void* d_ws, size_t ws_size,
                              hipStream_t stream) {
    const float* m    = (const float*)d_in[0];
    const unsigned* seqp = (const unsigned*)d_in[1];
    const unsigned* resp = (const unsigned*)d_in[2];
    const float* lng  = (const float*)d_in[3];
    const float* lnb  = (const float*)d_in[4];
    const float* Wq   = (const float*)d_in[5];
    const float* Wk   = (const float*)d_in[6];
    const float* Wv   = (const float*)d_in[7];
    const float* Wg   = (const float*)d_in[8];
    const float* bg   = (const float*)d_in[9];
    const float* Wo   = (const float*)d_in[10];
    const float* bo   = (const float*)d_in[11];
    float* out = (float*)d_out;

    char* p = (char*)d_ws;
    const size_t ABYTES = (size_t)Mrows * Dm * 2;      // 16.78 MB
    ushort* Whi = (ushort*)p;  p += 5 * 65536 * 2;
    ushort* Wlo = (ushort*)p;  p += 5 * 65536 * 2;
    ushort* qb  = (ushort*)p;  p += ABYTES;
    ushort* kb  = (ushort*)p;  p += ABYTES;
    ushort* vb  = (ushort*)p;  p += ABYTES;   // holds V^T planes
    ushort* gbf = (ushort*)p;  p += ABYTES;
    ushort* Ohi = (ushort*)p;  p += ABYTES;
    ushort* Olo = (ushort*)p;  p += ABYTES;
    float* qflag = (float*)p;  p += 1024;
    float* kbias = (float*)p;  p += 1024;

    ushort* Ahi = Ohi;   // alias: dead until attn2
    ushort* Alo = Olo;

    prep_all<<<8513, 256, 0, stream>>>(m, lng, lnb, Ahi, Alo,
                                       Wq, Wk, Wv, Wg, Wo, Whi, Wlo,
                                       seqp, resp, qflag, kbias);

    // qscale = 1/sqrt(32) * log2(e): softmax computed in exp2 domain.
    const float qscale = 0.17677669529663687f * 1.4426950408889634f;
    qkvg_fused<<<dim3(256, 4), 512, 0, stream>>>(Ahi, Alo, Whi, bg,
                                                 qb, kb, vb, gbf, qscale);

    attn2<<<dim3(8, 128), 256, 0, stream>>>(qb, kb, vb, gbf, qflag, kbias, Ohi, Olo);

    gemm_mfma<<<dim3(2, 256), 512, 0, stream>>>(Ohi, Olo, Whi + 4 * 65536, Wlo + 4 * 65536,
                                                bo, out);
}

// Round 13
// 194.105 us; speedup vs baseline: 1.0289x; 1.0289x over previous
//
#include <hip/hip_runtime.h>
#include <math.h>

#define NEG_INF -10000.0f
// NEG_INF * log2(e): masked scores live in exp2 domain now
#define NEG_INF_L2E -14426.950408889634f

typedef short bf16x8 __attribute__((ext_vector_type(8)));
typedef float f32x4 __attribute__((ext_vector_type(4)));
typedef unsigned u32x4 __attribute__((ext_vector_type(4)));

static constexpr int Dm = 256;   // model dim
static constexpr int Lm = 256;   // residues
static constexpr int Sm = 128;   // sequences
static constexpr int Mrows = Sm * Lm;  // 32768
static constexpr size_t HB = (size_t)Mrows * 32;  // head-plane stride (elems)

__device__ __forceinline__ ushort f2bf(float x) {
    unsigned u = __float_as_uint(x);
    unsigned r = (u + 0x7FFFu + ((u >> 16) & 1u)) >> 16;
    return (ushort)r;
}
__device__ __forceinline__ float bf2f(ushort h) {
    return __uint_as_float(((unsigned)h) << 16);
}
// packed f32x2 -> bf16x2 (RNE; bit-identical to f2bf for normals)
__device__ __forceinline__ unsigned cvtpk2(float a, float b) {
    unsigned r;
    asm("v_cvt_pk_bf16_f32 %0, %1, %2" : "=v"(r) : "v"(a), "v"(b));
    return r;
}
__device__ __forceinline__ void gload_lds16(const void* g, void* l) {
    __builtin_amdgcn_global_load_lds((__attribute__((address_space(1))) void*)g,
                                     (__attribute__((address_space(3))) void*)l,
                                     16, 0, 0);
}
__device__ __forceinline__ f32x4 mfma16(bf16x8 a, bf16x8 b, f32x4 c) {
    return __builtin_amdgcn_mfma_f32_16x16x32_bf16(a, b, c, 0, 0, 0);
}

// ---------------------------------------------------------------------------
// prep_all: one launch for LN+split (blocks [0,8192)), W hi/lo split
// (blocks [8192,8512): 5 mats x 64), mask decode (block 8512).
// ---------------------------------------------------------------------------
__global__ __launch_bounds__(256)
void prep_all(const float* __restrict__ m, const float* __restrict__ lng,
              const float* __restrict__ lnb,
              ushort* __restrict__ Ahi, ushort* __restrict__ Alo,
              const float* __restrict__ W0, const float* __restrict__ W1,
              const float* __restrict__ W2, const float* __restrict__ W3,
              const float* __restrict__ W4, ushort* __restrict__ Whi,
              ushort* __restrict__ Wlo,
              const unsigned* __restrict__ seq_raw,
              const unsigned* __restrict__ res_raw,
              float* __restrict__ qflag, float* __restrict__ kbias) {
    const int bx = blockIdx.x;
    if (bx < 8192) {
        // ---- LayerNorm + bf16 hi/lo split: one wave per row ----
        const int wid = threadIdx.x >> 6, lane = threadIdx.x & 63;
        const int row = (bx << 2) + wid;
        const float4 a = ((const float4*)(m + (size_t)row * Dm))[lane];
        float s  = a.x + a.y + a.z + a.w;
        float ss = a.x*a.x + a.y*a.y + a.z*a.z + a.w*a.w;
        #pragma unroll
        for (int off = 32; off > 0; off >>= 1) {
            s  += __shfl_xor(s, off);
            ss += __shfl_xor(ss, off);
        }
        const float mu = s * (1.0f / 256.0f);
        const float rs = rsqrtf(ss * (1.0f / 256.0f) - mu * mu + 1e-5f);
        const float4 g = ((const float4*)lng)[lane];
        const float4 b = ((const float4*)lnb)[lane];
        const float x0 = (a.x - mu) * rs * g.x + b.x;
        const float x1 = (a.y - mu) * rs * g.y + b.y;
        const float x2 = (a.z - mu) * rs * g.z + b.z;
        const float x3 = (a.w - mu) * rs * g.w + b.w;
        const unsigned h0 = cvtpk2(x0, x1);
        const unsigned h1 = cvtpk2(x2, x3);
        const float r0 = x0 - __uint_as_float(h0 << 16);
        const float r1 = x1 - __uint_as_float(h0 & 0xFFFF0000u);
        const float r2 = x2 - __uint_as_float(h1 << 16);
        const float r3 = x3 - __uint_as_float(h1 & 0xFFFF0000u);
        const unsigned l0 = cvtpk2(r0, r1);
        const unsigned l1 = cvtpk2(r2, r3);
        uint2 hv, lv;
        hv.x = h0; hv.y = h1;
        lv.x = l0; lv.y = l1;
        const size_t o = (size_t)row * 256 + 4 * lane;
        *(uint2*)(Ahi + o) = hv;
        *(uint2*)(Alo + o) = lv;
        return;
    }
    if (bx < 8512) {
        // ---- W hi/lo split, mats 0-3 even/odd row-permuted ----
        const int b = bx - 8192;
        const int mat = b >> 6, xb = b & 63;
        const float* Ws[5] = {W0, W1, W2, W3, W4};
        const size_t idx = ((size_t)xb * 256 + threadIdx.x) * 4;
        const float4 v = *(const float4*)(Ws[mat] + idx);
        ushort4 hi, lo;
        hi.x = f2bf(v.x); lo.x = f2bf(v.x - bf2f(hi.x));
        hi.y = f2bf(v.y); lo.y = f2bf(v.y - bf2f(hi.y));
        hi.z = f2bf(v.z); lo.z = f2bf(v.z - bf2f(hi.z));
        hi.w = f2bf(v.w); lo.w = f2bf(v.w - bf2f(hi.w));
        const int row = (int)(idx >> 8), col = (int)(idx & 255);
        int drow = row;
        if (mat < 4) {
            const int ch = row & 31;
            const int p = (ch & 1) ? 16 + (ch >> 1) : (ch >> 1);
            drow = (row & ~31) | p;
        }
        const size_t o = (size_t)mat * 65536 + (size_t)drow * 256 + col;
        *(ushort4*)(Whi + o) = hi;
        *(ushort4*)(Wlo + o) = lo;
        return;
    }
    // ---- mask decode (single block) ----
    __shared__ unsigned long long sb[4], sf[4];
    __shared__ int enc;
    const int t = threadIdx.x;
    unsigned w = 0;
    if (t < 64)        w = seq_raw[t];
    else if (t < 128)  w = res_raw[t - 64];
    bool bad = (w != 0u) && (w != 1u) && (w != 0x3f800000u);
    bool isf = (w == 0x3f800000u);
    unsigned long long bm = __ballot(bad);
    unsigned long long fm = __ballot(isf);
    const int wid = t >> 6;
    if ((t & 63) == 0) { sb[wid] = bm; sf[wid] = fm; }
    __syncthreads();
    if (t == 0) {
        unsigned long long B = sb[0] | sb[1];
        unsigned long long F = sf[0] | sf[1];
        enc = B ? 2 : (F ? 1 : 0);
    }
    __syncthreads();
    const int e = enc;
    int sv, rv;
    if (e == 2) {
        const unsigned char* sp = (const unsigned char*)seq_raw;
        const unsigned char* rp = (const unsigned char*)res_raw;
        sv = sp[t]; rv = rp[t];
    } else if (e == 1) {
        sv = (((const float*)seq_raw)[t] != 0.0f);
        rv = (((const float*)res_raw)[t] != 0.0f);
    } else {
        sv = (seq_raw[t] != 0u);
        rv = (res_raw[t] != 0u);
    }
    qflag[t] = sv ? NEG_INF : 0.0f;
    kbias[t] = rv ? NEG_INF_L2E : 0.0f;   // pre-scaled for exp2-domain softmax
}

// ---------------------------------------------------------------------------
// Fused QKVG GEMM v6 (frozen): 512-thread block, tile M=128 x N=256 (one
// matrix), per-wave 64x64, counted-vmcnt(4) dbuf pipeline, 64 KB.
// V (mat==2) stored PRE-TRANSPOSED in attn2's swizzled V^T plane layout.
// qscale includes log2(e) (softmax runs in exp2 domain).
// ---------------------------------------------------------------------------
__global__ __launch_bounds__(512, 4)
void qkvg_fused(const ushort* __restrict__ Ahig, const ushort* __restrict__ Alog,
                const ushort* __restrict__ Whi, const float* __restrict__ bg,
                ushort* __restrict__ qb, ushort* __restrict__ kb,
                ushort* __restrict__ vb, ushort* __restrict__ gbf,
                float qscale) {
    __shared__ __align__(16) ushort Wh[2][256 * 32];   // 2 x 16 KB
    __shared__ __align__(16) ushort Ah[2][128 * 32];   // 2 x 8 KB
    __shared__ __align__(16) ushort Al[2][128 * 32];   // 2 x 8 KB
    const int tid = threadIdx.x, lane = tid & 63, wave = tid >> 6;
    const int li = lane & 15, quad = lane >> 4;
    const int m0 = blockIdx.x << 7;         // m-tile (fastest), M=128
    const int mat = blockIdx.y;             // matrix 0..3
    const int wm = (wave >> 2) << 6;        // wave m-half: 0 / 64
    const int wn = (wave & 3) << 6;         // wave n-slice: 0/64/128/192

    const int l4 = lane >> 2, slot = lane & 3;

    f32x4 zero = {0.f, 0.f, 0.f, 0.f};
    f32x4 acc[4][4];
    #pragma unroll
    for (int i = 0; i < 4; ++i)
        #pragma unroll
        for (int j = 0; j < 4; ++j) acc[i][j] = zero;

    const ushort* Wmat = Whi + (size_t)mat * 65536;

#define STAGE(kt, buf) do {                                                    \
    _Pragma("unroll")                                                          \
    for (int j_ = 0; j_ < 2; ++j_) {                                           \
        const int wrow_ = wave * 32 + j_ * 16 + l4;                            \
        const int wsw_ = (wrow_ & 3) ^ ((wrow_ >> 2) & 3);                     \
        gload_lds16(Wmat + (size_t)wrow_ * 256 + (kt) + ((slot ^ wsw_) << 3),  \
                    &Wh[buf][wave * 1024 + j_ * 512]);                         \
    }                                                                          \
    {                                                                          \
        const int arow_ = wave * 16 + l4;                                      \
        const int asw_ = (arow_ & 3) ^ ((arow_ >> 2) & 3);                     \
        const size_t asrc_ = (size_t)(m0 + arow_) * 256 + (kt) + ((slot ^ asw_) << 3); \
        gload_lds16(Ahig + asrc_, &Ah[buf][wave * 512]);                       \
        gload_lds16(Alog + asrc_, &Al[buf][wave * 512]);                       \
    } } while (0)

#define COMPUTE(buf) do {                                                      \
    bf16x8 ah_[4], al_[4];                                                     \
    _Pragma("unroll")                                                          \
    for (int mt_ = 0; mt_ < 4; ++mt_) {                                        \
        const int r_ = wm + mt_ * 16 + li;                                     \
        const int sw_ = (r_ & 3) ^ ((r_ >> 2) & 3);                            \
        const int off_ = r_ * 32 + ((quad ^ sw_) << 3);                        \
        ah_[mt_] = *(const bf16x8*)&Ah[buf][off_];                             \
        al_[mt_] = *(const bf16x8*)&Al[buf][off_];                             \
    }                                                                          \
    _Pragma("unroll")                                                          \
    for (int nt_ = 0; nt_ < 4; ++nt_) {                                        \
        const int rn_ = wn + nt_ * 16 + li;                                    \
        const int sw_ = (rn_ & 3) ^ ((rn_ >> 2) & 3);                          \
        const bf16x8 bh_ = *(const bf16x8*)&Wh[buf][rn_ * 32 + ((quad ^ sw_) << 3)]; \
        _Pragma("unroll")                                                      \
        for (int mt_ = 0; mt_ < 4; ++mt_) {                                    \
            acc[mt_][nt_] = mfma16(ah_[mt_], bh_, acc[mt_][nt_]);              \
            acc[mt_][nt_] = mfma16(al_[mt_], bh_, acc[mt_][nt_]);              \
        }                                                                      \
    } } while (0)

    STAGE(0, 0);
    int cur = 0;
    for (int kt = 32; kt < 256; kt += 32) {
        STAGE(kt, cur ^ 1);                       // 4 loads -> in flight
        asm volatile("s_waitcnt vmcnt(4)\n\ts_barrier" ::: "memory");
        COMPUTE(cur);
        asm volatile("s_barrier" ::: "memory");   // readers done before overwrite
        cur ^= 1;
    }
    asm volatile("s_waitcnt vmcnt(0)\n\ts_barrier" ::: "memory");
    COMPUTE(cur);                                 // last tile

#undef STAGE
#undef COMPUTE

    if (mat == 2) {
        // V epilogue: store into attn2's swizzled V^T plane layout.
        const int s = m0 >> 8;                    // sequence of this 128-row tile
        const int keyOff = m0 & 255;              // 0 or 128 within the plane
        #pragma unroll
        for (int j = 0; j < 2; ++j) {
            const int hh = (wave & 3) * 2 + j;
            #pragma unroll
            for (int mt = 0; mt < 4; ++mt) {
                const int key = keyOff + wm + mt * 16 + quad * 4;  // r=0 key
                const int vkb = key >> 5, vq = (key >> 3) & 3, vj0 = key & 7;
                const int vsw = (4 * vkb + vq) & 7;
                const size_t pb = (size_t)hh * HB + (size_t)s * 8192
                                + vkb * 1024 + vq * 128 + ((li ^ vsw) << 3) + vj0;
                uint2 uE, uO;
                uE.x = cvtpk2(acc[mt][2 * j][0],     acc[mt][2 * j][1]);
                uE.y = cvtpk2(acc[mt][2 * j][2],     acc[mt][2 * j][3]);
                uO.x = cvtpk2(acc[mt][2 * j + 1][0], acc[mt][2 * j + 1][1]);
                uO.y = cvtpk2(acc[mt][2 * j + 1][2], acc[mt][2 * j + 1][3]);
                *(uint2*)&vb[pb]       = uE;
                *(uint2*)&vb[pb + 512] = uO;
            }
        }
    } else {
        ushort* outp = (mat == 0) ? qb : (mat == 1) ? kb : gbf;
        #pragma unroll
        for (int j = 0; j < 2; ++j) {
            const int hh = (wave & 3) * 2 + j;
            const int cE = hh * 32 + 2 * li;
            const float2 bg2 = *(const float2*)(bg + cE);
            #pragma unroll
            for (int mt = 0; mt < 4; ++mt) {
                #pragma unroll
                for (int r = 0; r < 4; ++r) {
                    const int row = m0 + wm + mt * 16 + quad * 4 + r;
                    float vE = acc[mt][2 * j][r];
                    float vO = acc[mt][2 * j + 1][r];
                    if (mat == 0) { vE *= qscale; vO *= qscale; }
                    if (mat == 3) {
                        vE = 1.0f / (1.0f + __expf(-(vE + bg2.x)));
                        vO = 1.0f / (1.0f + __expf(-(vO + bg2.y)));
                    }
                    const unsigned u = cvtpk2(vE, vO);
                    *(unsigned*)&outp[(size_t)hh * HB + (size_t)row * 32 + 2 * li] = u;
                }
            }
        }
    }
}

// ---------------------------------------------------------------------------
// Attention v10: O stored HI-ONLY (Olo dropped; error analysis: +~4e-4 on
// final out, an order below current absmax). exp2-domain softmax, no max
// pass. V pre-transposed; Q/G direct from global.
// ---------------------------------------------------------------------------
__global__ __launch_bounds__(256, 2)
void attn2(const ushort* __restrict__ Qb, const ushort* __restrict__ Kb,
           const ushort* __restrict__ Vtb, const ushort* __restrict__ Gb,
           const float* __restrict__ qflag, const float* __restrict__ kbias,
           ushort* __restrict__ Ohi) {
    __shared__ __align__(16) ushort Kl[8192];   // 16 KB swizzled K
    __shared__ __align__(16) ushort Vt[8192];   // 16 KB paired/swizzled V^T
    const int h = blockIdx.x, s = blockIdx.y;
    const int tid = threadIdx.x, lane = tid & 63, wave = tid >> 6;
    const int li = lane & 15, quad = lane >> 4;
    const size_t base = (size_t)h * HB + (size_t)s * 8192;

    // --- K staging (XOR-swizzled, global_load_lds) ---
    const int srow = tid >> 2, slot = tid & 3;
    const int sw0 = (srow & 3) ^ ((srow >> 2) & 3);
    const int gk0 = (slot ^ sw0) << 3;
    #pragma unroll
    for (int i = 0; i < 4; ++i) {
        const int r = i * 64 + srow;
        gload_lds16(Kb + base + (size_t)r * 32 + gk0, &Kl[i * 2048 + wave * 512]);
    }
    // --- V^T staging: linear copy (layout pre-arranged by qkvg) ---
    #pragma unroll
    for (int i = 0; i < 4; ++i) {
        const int off = i * 2048 + wave * 512;
        gload_lds16(Vtb + base + off + (lane << 3), &Vt[off]);
    }
    __syncthreads();

    f32x4 zero = {0.f, 0.f, 0.f, 0.f};

    for (int chunk = 0; chunk < 4; ++chunk) {
        const int q0 = wave * 64 + chunk * 16;     // query base (residue)
        const bf16x8 qf = *(const bf16x8*)(Qb + base + (size_t)(q0 + li) * 32 + quad * 8);
        const float kmul = (qflag[q0 + li] != 0.0f) ? 0.0f : 1.0f;
        unsigned gpre[4];
        #pragma unroll
        for (int r = 0; r < 4; ++r)
            gpre[r] = *(const unsigned*)(Gb + base +
                          (size_t)(q0 + 4 * quad + r) * 32 + 2 * li);

        f32x4 sc[16];
        __builtin_amdgcn_s_setprio(1);
        #pragma unroll
        for (int t = 0; t < 16; ++t) {
            const int kr = (t >> 1) * 32 + ((li >> 2) << 3) + ((t & 1) << 2) + (li & 3);
            const int sw = (kr & 3) ^ ((kr >> 2) & 3);
            const bf16x8 kf = *(const bf16x8*)&Kl[kr * 32 + ((quad ^ sw) << 3)];
            sc[t] = mfma16(kf, qf, zero);
        }
        __builtin_amdgcn_s_setprio(0);
        // bias + exp2 + sum (exp2 domain; masked -> exp2(-14427) == 0)
        float ls = 0.0f;
        #pragma unroll
        for (int t = 0; t < 16; ++t) {
            const float4 kb4 = ((const float4*)kbias)[(t >> 1) * 8 + quad * 2 + (t & 1)];
            sc[t][0] = exp2f(kmul * kb4.x + sc[t][0]);
            sc[t][1] = exp2f(kmul * kb4.y + sc[t][1]);
            sc[t][2] = exp2f(kmul * kb4.z + sc[t][2]);
            sc[t][3] = exp2f(kmul * kb4.w + sc[t][3]);
            ls += sc[t][0] + sc[t][1] + sc[t][2] + sc[t][3];
        }
        ls += __shfl_xor(ls, 16);
        ls += __shfl_xor(ls, 32);
        const float inv_own = 1.0f / ls;

        f32x4 a0 = zero, a1 = zero;
        __builtin_amdgcn_s_setprio(1);
        #pragma unroll
        for (int kbk = 0; kbk < 8; ++kbk) {
            u32x4 pu;
            pu[0] = cvtpk2(sc[2 * kbk][0],     sc[2 * kbk][1]);
            pu[1] = cvtpk2(sc[2 * kbk][2],     sc[2 * kbk][3]);
            pu[2] = cvtpk2(sc[2 * kbk + 1][0], sc[2 * kbk + 1][1]);
            pu[3] = cvtpk2(sc[2 * kbk + 1][2], sc[2 * kbk + 1][3]);
            const bf16x8 pf = __builtin_bit_cast(bf16x8, pu);
            const int vsw = (4 * kbk + quad) & 7;
            const bf16x8 v0 = *(const bf16x8*)&Vt[kbk * 1024 + quad * 128 + ((li ^ vsw) << 3)];
            const bf16x8 v1 = *(const bf16x8*)&Vt[kbk * 1024 + 512 + quad * 128 + ((li ^ vsw) << 3)];
            a0 = mfma16(pf, v0, a0);
            a1 = mfma16(pf, v1, a1);
        }
        __builtin_amdgcn_s_setprio(0);
        #pragma unroll
        for (int r = 0; r < 4; ++r) {
            const float inv = __shfl(inv_own, 4 * quad + r);
            const int rowq = q0 + 4 * quad + r;
            const size_t ro = base + (size_t)rowq * 32;
            const unsigned gu = gpre[r];
            const float g0 = bf2f((ushort)(gu & 0xFFFFu));
            const float g1 = bf2f((ushort)(gu >> 16));
            const float x0 = a0[r] * inv * g0;
            const float x1 = a1[r] * inv * g1;
            *(unsigned*)&Ohi[ro + 2 * li] = cvtpk2(x0, x1);
        }
    }
}

// ---------------------------------------------------------------------------
// Final GEMM v4: O hi-only -> 2-term product (Ahi x (Whi+Wlo)). 3 loads/tile
// (vmcnt(3)), 48 KB LDS dbuf. 512-thread / 8-wave, M128 x N128, per-wave
// 64x32, counted-vmcnt pipeline, fp32 out + bias.
// ---------------------------------------------------------------------------
__global__ __launch_bounds__(512, 4)
void gemm_mfma(const ushort* __restrict__ Ahi,
               const ushort* __restrict__ Whi, const ushort* __restrict__ Wlo,
               const float* __restrict__ bias, float* __restrict__ outp) {
    __shared__ __align__(16) ushort lds[2][12288];
    const int tid = threadIdx.x;
    const int lane = tid & 63, wave = tid >> 6;
    const int li = lane & 15, quad = lane >> 4;
    const int m0 = blockIdx.y << 7, n0 = blockIdx.x << 7;
    const int wm = (wave >> 2) << 6;        // 0 / 64
    const int wn = (wave & 3) << 5;         // 0 / 32 / 64 / 96
    const int srow = tid >> 2, slot = tid & 3;   // srow in [0,128)
    const int sw0 = (srow & 3) ^ ((srow >> 2) & 3);
    const int gk0 = (slot ^ sw0) << 3;

    f32x4 zero = {0.f, 0.f, 0.f, 0.f};
    f32x4 acc[4][2];
    #pragma unroll
    for (int i = 0; i < 4; ++i)
        #pragma unroll
        for (int j = 0; j < 2; ++j) acc[i][j] = zero;

#define GSTAGE(kt, buf) do {                                                   \
    const size_t hplane_ = (size_t)((kt) >> 5) * HB;                           \
    const size_t ao_ = hplane_ + (size_t)(m0 + srow) * 32 + gk0;               \
    const size_t wo_ = (size_t)(n0 + srow) * 256 + (kt) + gk0;                 \
    gload_lds16(Ahi + ao_, &lds[buf][wave * 512]);                             \
    gload_lds16(Whi + wo_, &lds[buf][4096 + wave * 512]);                      \
    gload_lds16(Wlo + wo_, &lds[buf][8192 + wave * 512]);                      \
    } while (0)

#define GCOMPUTE(buf) do {                                                     \
    bf16x8 ah_[4], bh_[2], bl_[2];                                             \
    _Pragma("unroll")                                                          \
    for (int mt_ = 0; mt_ < 4; ++mt_) {                                        \
        const int r_ = wm + mt_ * 16 + li;                                     \
        const int sw_ = (r_ & 3) ^ ((r_ >> 2) & 3);                            \
        const int off_ = r_ * 32 + ((quad ^ sw_) << 3);                        \
        ah_[mt_] = *(const bf16x8*)&lds[buf][off_];                            \
    }                                                                          \
    _Pragma("unroll")                                                          \
    for (int nt_ = 0; nt_ < 2; ++nt_) {                                        \
        const int r_ = wn + nt_ * 16 + li;                                     \
        const int sw_ = (r_ & 3) ^ ((r_ >> 2) & 3);                            \
        const int off_ = r_ * 32 + ((quad ^ sw_) << 3);                        \
        bh_[nt_] = *(const bf16x8*)&lds[buf][4096 + off_];                     \
        bl_[nt_] = *(const bf16x8*)&lds[buf][8192 + off_];                     \
    }                                                                          \
    _Pragma("unroll")                                                          \
    for (int mt_ = 0; mt_ < 4; ++mt_)                                          \
        _Pragma("unroll")                                                      \
        for (int nt_ = 0; nt_ < 2; ++nt_) {                                    \
            acc[mt_][nt_] = mfma16(ah_[mt_], bh_[nt_], acc[mt_][nt_]);         \
            acc[mt_][nt_] = mfma16(ah_[mt_], bl_[nt_], acc[mt_][nt_]);         \
        } } while (0)

    GSTAGE(0, 0);
    int cur = 0;
    for (int kt = 32; kt < 256; kt += 32) {
        GSTAGE(kt, cur ^ 1);                      // 3 loads in flight
        asm volatile("s_waitcnt vmcnt(3)\n\ts_barrier" ::: "memory");
        GCOMPUTE(cur);
        asm volatile("s_barrier" ::: "memory");
        cur ^= 1;
    }
    asm volatile("s_waitcnt vmcnt(0)\n\ts_barrier" ::: "memory");
    GCOMPUTE(cur);

#undef GSTAGE
#undef GCOMPUTE

    #pragma unroll
    for (int mt = 0; mt < 4; ++mt) {
        const int rowb = m0 + wm + mt * 16 + quad * 4;
        #pragma unroll
        for (int nt = 0; nt < 2; ++nt) {
            const int col = n0 + wn + nt * 16 + li;
            const float bv = bias[col];
            #pragma unroll
            for (int r = 0; r < 4; ++r) {
                const size_t o = (size_t)(rowb + r) * 256 + col;
                outp[o] = acc[mt][nt][r] + bv;
            }
        }
    }
}

// ---------------------------------------------------------------------------
// Launch. Ahi/Alo (normalized input, bf16 hi/lo) ALIAS Ohi/OloSlot: dead by
// the time attn2 writes Ohi (qkvg consumed A first; stream-ordered).
// ---------------------------------------------------------------------------
extern "C" void kernel_launch(void* const* d_in, const int* in_sizes, int n_in,
                              void* d_out, int out_size, void* d_ws, size_t ws_size,
                              hipStream_t stream) {
    const float* m    = (const float*)d_in[0];
    const unsigned* seqp = (const unsigned*)d_in[1];
    const unsigned* resp = (const unsigned*)d_in[2];
    const float* lng  = (const float*)d_in[3];
    const float* lnb  = (const float*)d_in[4];
    const float* Wq   = (const float*)d_in[5];
    const float* Wk   = (const float*)d_in[6];
    const float* Wv   = (const float*)d_in[7];
    const float* Wg   = (const float*)d_in[8];
    const float* bg   = (const float*)d_in[9];
    const float* Wo   = (const float*)d_in[10];
    const float* bo   = (const float*)d_in[11];
    float* out = (float*)d_out;

    char* p = (char*)d_ws;
    const size_t ABYTES = (size_t)Mrows * Dm * 2;      // 16.78 MB
    ushort* Whi = (ushort*)p;  p += 5 * 65536 * 2;
    ushort* Wlo = (ushort*)p;  p += 5 * 65536 * 2;
    ushort* qb  = (ushort*)p;  p += ABYTES;
    ushort* kb  = (ushort*)p;  p += ABYTES;
    ushort* vb  = (ushort*)p;  p += ABYTES;   // holds V^T planes
    ushort* gbf = (ushort*)p;  p += ABYTES;
    ushort* Ohi = (ushort*)p;  p += ABYTES;
    ushort* AloBuf = (ushort*)p;  p += ABYTES;  // LN lo part (dead after qkvg)
    float* qflag = (float*)p;  p += 1024;
    float* kbias = (float*)p;  p += 1024;

    ushort* Ahi = Ohi;     // alias: dead until attn2 writes Ohi
    ushort* Alo = AloBuf;

    prep_all<<<8513, 256, 0, stream>>>(m, lng, lnb, Ahi, Alo,
                                       Wq, Wk, Wv, Wg, Wo, Whi, Wlo,
                                       seqp, resp, qflag, kbias);

    // qscale = 1/sqrt(32) * log2(e): softmax computed in exp2 domain.
    const float qscale = 0.17677669529663687f * 1.4426950408889634f;
    qkvg_fused<<<dim3(256, 4), 512, 0, stream>>>(Ahi, Alo, Whi, bg,
                                                 qb, kb, vb, gbf, qscale);

    attn2<<<dim3(8, 128), 256, 0, stream>>>(qb, kb, vb, gbf, qflag, kbias, Ohi);

    gemm_mfma<<<dim3(2, 256), 512, 0, stream>>>(Ohi, Whi + 4 * 65536, Wlo + 4 * 65536,
                                                bo, out);
}

// Round 14
// 181.100 us; speedup vs baseline: 1.1028x; 1.0718x over previous
//
#include <hip/hip_runtime.h>
#include <math.h>

#define NEG_INF -10000.0f
// NEG_INF * log2(e): masked scores live in exp2 domain now
#define NEG_INF_L2E -14426.950408889634f

typedef short bf16x8 __attribute__((ext_vector_type(8)));
typedef float f32x4 __attribute__((ext_vector_type(4)));
typedef unsigned u32x4 __attribute__((ext_vector_type(4)));

static constexpr int Dm = 256;   // model dim
static constexpr int Lm = 256;   // residues
static constexpr int Sm = 128;   // sequences
static constexpr int Mrows = Sm * Lm;  // 32768
static constexpr size_t HB = (size_t)Mrows * 32;  // head-plane stride (elems)

__device__ __forceinline__ ushort f2bf(float x) {
    unsigned u = __float_as_uint(x);
    unsigned r = (u + 0x7FFFu + ((u >> 16) & 1u)) >> 16;
    return (ushort)r;
}
__device__ __forceinline__ float bf2f(ushort h) {
    return __uint_as_float(((unsigned)h) << 16);
}
// packed f32x2 -> bf16x2 (RNE; bit-identical to f2bf for normals)
__device__ __forceinline__ unsigned cvtpk2(float a, float b) {
    unsigned r;
    asm("v_cvt_pk_bf16_f32 %0, %1, %2" : "=v"(r) : "v"(a), "v"(b));
    return r;
}
__device__ __forceinline__ void gload_lds16(const void* g, void* l) {
    __builtin_amdgcn_global_load_lds((__attribute__((address_space(1))) void*)g,
                                     (__attribute__((address_space(3))) void*)l,
                                     16, 0, 0);
}
__device__ __forceinline__ f32x4 mfma16(bf16x8 a, bf16x8 b, f32x4 c) {
    return __builtin_amdgcn_mfma_f32_16x16x32_bf16(a, b, c, 0, 0, 0);
}

// ---------------------------------------------------------------------------
// prep_all: one launch for LN (blocks [0,8192)), W hi/lo split
// (blocks [8192,8512): 5 mats x 64), mask decode (block 8512).
// A is stored HI-ONLY now (A-lo dropped; error analysis: qkvg already
// carries W-bf16 quantization of the same magnitude, outputs are bf16).
// ---------------------------------------------------------------------------
__global__ __launch_bounds__(256)
void prep_all(const float* __restrict__ m, const float* __restrict__ lng,
              const float* __restrict__ lnb,
              ushort* __restrict__ Ahi,
              const float* __restrict__ W0, const float* __restrict__ W1,
              const float* __restrict__ W2, const float* __restrict__ W3,
              const float* __restrict__ W4, ushort* __restrict__ Whi,
              ushort* __restrict__ Wlo,
              const unsigned* __restrict__ seq_raw,
              const unsigned* __restrict__ res_raw,
              float* __restrict__ qflag, float* __restrict__ kbias) {
    const int bx = blockIdx.x;
    if (bx < 8192) {
        // ---- LayerNorm + bf16 (hi only): one wave per row ----
        const int wid = threadIdx.x >> 6, lane = threadIdx.x & 63;
        const int row = (bx << 2) + wid;
        const float4 a = ((const float4*)(m + (size_t)row * Dm))[lane];
        float s  = a.x + a.y + a.z + a.w;
        float ss = a.x*a.x + a.y*a.y + a.z*a.z + a.w*a.w;
        #pragma unroll
        for (int off = 32; off > 0; off >>= 1) {
            s  += __shfl_xor(s, off);
            ss += __shfl_xor(ss, off);
        }
        const float mu = s * (1.0f / 256.0f);
        const float rs = rsqrtf(ss * (1.0f / 256.0f) - mu * mu + 1e-5f);
        const float4 g = ((const float4*)lng)[lane];
        const float4 b = ((const float4*)lnb)[lane];
        const float x0 = (a.x - mu) * rs * g.x + b.x;
        const float x1 = (a.y - mu) * rs * g.y + b.y;
        const float x2 = (a.z - mu) * rs * g.z + b.z;
        const float x3 = (a.w - mu) * rs * g.w + b.w;
        uint2 hv;
        hv.x = cvtpk2(x0, x1);
        hv.y = cvtpk2(x2, x3);
        const size_t o = (size_t)row * 256 + 4 * lane;
        *(uint2*)(Ahi + o) = hv;
        return;
    }
    if (bx < 8512) {
        // ---- W hi/lo split, mats 0-3 even/odd row-permuted ----
        const int b = bx - 8192;
        const int mat = b >> 6, xb = b & 63;
        const float* Ws[5] = {W0, W1, W2, W3, W4};
        const size_t idx = ((size_t)xb * 256 + threadIdx.x) * 4;
        const float4 v = *(const float4*)(Ws[mat] + idx);
        ushort4 hi, lo;
        hi.x = f2bf(v.x); lo.x = f2bf(v.x - bf2f(hi.x));
        hi.y = f2bf(v.y); lo.y = f2bf(v.y - bf2f(hi.y));
        hi.z = f2bf(v.z); lo.z = f2bf(v.z - bf2f(hi.z));
        hi.w = f2bf(v.w); lo.w = f2bf(v.w - bf2f(hi.w));
        const int row = (int)(idx >> 8), col = (int)(idx & 255);
        int drow = row;
        if (mat < 4) {
            const int ch = row & 31;
            const int p = (ch & 1) ? 16 + (ch >> 1) : (ch >> 1);
            drow = (row & ~31) | p;
        }
        const size_t o = (size_t)mat * 65536 + (size_t)drow * 256 + col;
        *(ushort4*)(Whi + o) = hi;
        *(ushort4*)(Wlo + o) = lo;
        return;
    }
    // ---- mask decode (single block) ----
    __shared__ unsigned long long sb[4], sf[4];
    __shared__ int enc;
    const int t = threadIdx.x;
    unsigned w = 0;
    if (t < 64)        w = seq_raw[t];
    else if (t < 128)  w = res_raw[t - 64];
    bool bad = (w != 0u) && (w != 1u) && (w != 0x3f800000u);
    bool isf = (w == 0x3f800000u);
    unsigned long long bm = __ballot(bad);
    unsigned long long fm = __ballot(isf);
    const int wid = t >> 6;
    if ((t & 63) == 0) { sb[wid] = bm; sf[wid] = fm; }
    __syncthreads();
    if (t == 0) {
        unsigned long long B = sb[0] | sb[1];
        unsigned long long F = sf[0] | sf[1];
        enc = B ? 2 : (F ? 1 : 0);
    }
    __syncthreads();
    const int e = enc;
    int sv, rv;
    if (e == 2) {
        const unsigned char* sp = (const unsigned char*)seq_raw;
        const unsigned char* rp = (const unsigned char*)res_raw;
        sv = sp[t]; rv = rp[t];
    } else if (e == 1) {
        sv = (((const float*)seq_raw)[t] != 0.0f);
        rv = (((const float*)res_raw)[t] != 0.0f);
    } else {
        sv = (seq_raw[t] != 0u);
        rv = (res_raw[t] != 0u);
    }
    qflag[t] = sv ? NEG_INF : 0.0f;
    kbias[t] = rv ? NEG_INF_L2E : 0.0f;   // pre-scaled for exp2-domain softmax
}

// ---------------------------------------------------------------------------
// Fused QKVG GEMM v8: A HI-ONLY -> single-term product (ah x bh). 3 loads/
// tile (vmcnt(3)), 48 KB LDS dbuf, 16 MFMA per wave-tile (was 32).
// 512-thread block, tile M=128 x N=256, per-wave 64x64.
// V (mat==2) stored PRE-TRANSPOSED in attn2's swizzled V^T plane layout.
// qscale includes log2(e) (softmax runs in exp2 domain).
// ---------------------------------------------------------------------------
__global__ __launch_bounds__(512, 4)
void qkvg_fused(const ushort* __restrict__ Ahig,
                const ushort* __restrict__ Whi, const float* __restrict__ bg,
                ushort* __restrict__ qb, ushort* __restrict__ kb,
                ushort* __restrict__ vb, ushort* __restrict__ gbf,
                float qscale) {
    __shared__ __align__(16) ushort Wh[2][256 * 32];   // 2 x 16 KB
    __shared__ __align__(16) ushort Ah[2][128 * 32];   // 2 x 8 KB
    const int tid = threadIdx.x, lane = tid & 63, wave = tid >> 6;
    const int li = lane & 15, quad = lane >> 4;
    const int m0 = blockIdx.x << 7;         // m-tile (fastest), M=128
    const int mat = blockIdx.y;             // matrix 0..3
    const int wm = (wave >> 2) << 6;        // wave m-half: 0 / 64
    const int wn = (wave & 3) << 6;         // wave n-slice: 0/64/128/192

    const int l4 = lane >> 2, slot = lane & 3;

    f32x4 zero = {0.f, 0.f, 0.f, 0.f};
    f32x4 acc[4][4];
    #pragma unroll
    for (int i = 0; i < 4; ++i)
        #pragma unroll
        for (int j = 0; j < 4; ++j) acc[i][j] = zero;

    const ushort* Wmat = Whi + (size_t)mat * 65536;

#define STAGE(kt, buf) do {                                                    \
    _Pragma("unroll")                                                          \
    for (int j_ = 0; j_ < 2; ++j_) {                                           \
        const int wrow_ = wave * 32 + j_ * 16 + l4;                            \
        const int wsw_ = (wrow_ & 3) ^ ((wrow_ >> 2) & 3);                     \
        gload_lds16(Wmat + (size_t)wrow_ * 256 + (kt) + ((slot ^ wsw_) << 3),  \
                    &Wh[buf][wave * 1024 + j_ * 512]);                         \
    }                                                                          \
    {                                                                          \
        const int arow_ = wave * 16 + l4;                                      \
        const int asw_ = (arow_ & 3) ^ ((arow_ >> 2) & 3);                     \
        const size_t asrc_ = (size_t)(m0 + arow_) * 256 + (kt) + ((slot ^ asw_) << 3); \
        gload_lds16(Ahig + asrc_, &Ah[buf][wave * 512]);                       \
    } } while (0)

#define COMPUTE(buf) do {                                                      \
    bf16x8 ah_[4];                                                             \
    _Pragma("unroll")                                                          \
    for (int mt_ = 0; mt_ < 4; ++mt_) {                                        \
        const int r_ = wm + mt_ * 16 + li;                                     \
        const int sw_ = (r_ & 3) ^ ((r_ >> 2) & 3);                            \
        const int off_ = r_ * 32 + ((quad ^ sw_) << 3);                        \
        ah_[mt_] = *(const bf16x8*)&Ah[buf][off_];                             \
    }                                                                          \
    _Pragma("unroll")                                                          \
    for (int nt_ = 0; nt_ < 4; ++nt_) {                                        \
        const int rn_ = wn + nt_ * 16 + li;                                    \
        const int sw_ = (rn_ & 3) ^ ((rn_ >> 2) & 3);                          \
        const bf16x8 bh_ = *(const bf16x8*)&Wh[buf][rn_ * 32 + ((quad ^ sw_) << 3)]; \
        _Pragma("unroll")                                                      \
        for (int mt_ = 0; mt_ < 4; ++mt_) {                                    \
            acc[mt_][nt_] = mfma16(ah_[mt_], bh_, acc[mt_][nt_]);              \
        }                                                                      \
    } } while (0)

    STAGE(0, 0);
    int cur = 0;
    for (int kt = 32; kt < 256; kt += 32) {
        STAGE(kt, cur ^ 1);                       // 3 loads -> in flight
        asm volatile("s_waitcnt vmcnt(3)\n\ts_barrier" ::: "memory");
        COMPUTE(cur);
        asm volatile("s_barrier" ::: "memory");   // readers done before overwrite
        cur ^= 1;
    }
    asm volatile("s_waitcnt vmcnt(0)\n\ts_barrier" ::: "memory");
    COMPUTE(cur);                                 // last tile

#undef STAGE
#undef COMPUTE

    if (mat == 2) {
        // V epilogue: store into attn2's swizzled V^T plane layout.
        const int s = m0 >> 8;                    // sequence of this 128-row tile
        const int keyOff = m0 & 255;              // 0 or 128 within the plane
        #pragma unroll
        for (int j = 0; j < 2; ++j) {
            const int hh = (wave & 3) * 2 + j;
            #pragma unroll
            for (int mt = 0; mt < 4; ++mt) {
                const int key = keyOff + wm + mt * 16 + quad * 4;  // r=0 key
                const int vkb = key >> 5, vq = (key >> 3) & 3, vj0 = key & 7;
                const int vsw = (4 * vkb + vq) & 7;
                const size_t pb = (size_t)hh * HB + (size_t)s * 8192
                                + vkb * 1024 + vq * 128 + ((li ^ vsw) << 3) + vj0;
                uint2 uE, uO;
                uE.x = cvtpk2(acc[mt][2 * j][0],     acc[mt][2 * j][1]);
                uE.y = cvtpk2(acc[mt][2 * j][2],     acc[mt][2 * j][3]);
                uO.x = cvtpk2(acc[mt][2 * j + 1][0], acc[mt][2 * j + 1][1]);
                uO.y = cvtpk2(acc[mt][2 * j + 1][2], acc[mt][2 * j + 1][3]);
                *(uint2*)&vb[pb]       = uE;
                *(uint2*)&vb[pb + 512] = uO;
            }
        }
    } else {
        ushort* outp = (mat == 0) ? qb : (mat == 1) ? kb : gbf;
        #pragma unroll
        for (int j = 0; j < 2; ++j) {
            const int hh = (wave & 3) * 2 + j;
            const int cE = hh * 32 + 2 * li;
            const float2 bg2 = *(const float2*)(bg + cE);
            #pragma unroll
            for (int mt = 0; mt < 4; ++mt) {
                #pragma unroll
                for (int r = 0; r < 4; ++r) {
                    const int row = m0 + wm + mt * 16 + quad * 4 + r;
                    float vE = acc[mt][2 * j][r];
                    float vO = acc[mt][2 * j + 1][r];
                    if (mat == 0) { vE *= qscale; vO *= qscale; }
                    if (mat == 3) {
                        vE = 1.0f / (1.0f + __expf(-(vE + bg2.x)));
                        vO = 1.0f / (1.0f + __expf(-(vO + bg2.y)));
                    }
                    const unsigned u = cvtpk2(vE, vO);
                    *(unsigned*)&outp[(size_t)hh * HB + (size_t)row * 32 + 2 * li] = u;
                }
            }
        }
    }
}

// ---------------------------------------------------------------------------
// Attention v10 (unchanged): O hi-only, exp2-domain softmax, no max pass,
// V pre-transposed; Q/G direct from global.
// ---------------------------------------------------------------------------
__global__ __launch_bounds__(256, 2)
void attn2(const ushort* __restrict__ Qb, const ushort* __restrict__ Kb,
           const ushort* __restrict__ Vtb, const ushort* __restrict__ Gb,
           const float* __restrict__ qflag, const float* __restrict__ kbias,
           ushort* __restrict__ Ohi) {
    __shared__ __align__(16) ushort Kl[8192];   // 16 KB swizzled K
    __shared__ __align__(16) ushort Vt[8192];   // 16 KB paired/swizzled V^T
    const int h = blockIdx.x, s = blockIdx.y;
    const int tid = threadIdx.x, lane = tid & 63, wave = tid >> 6;
    const int li = lane & 15, quad = lane >> 4;
    const size_t base = (size_t)h * HB + (size_t)s * 8192;

    // --- K staging (XOR-swizzled, global_load_lds) ---
    const int srow = tid >> 2, slot = tid & 3;
    const int sw0 = (srow & 3) ^ ((srow >> 2) & 3);
    const int gk0 = (slot ^ sw0) << 3;
    #pragma unroll
    for (int i = 0; i < 4; ++i) {
        const int r = i * 64 + srow;
        gload_lds16(Kb + base + (size_t)r * 32 + gk0, &Kl[i * 2048 + wave * 512]);
    }
    // --- V^T staging: linear copy (layout pre-arranged by qkvg) ---
    #pragma unroll
    for (int i = 0; i < 4; ++i) {
        const int off = i * 2048 + wave * 512;
        gload_lds16(Vtb + base + off + (lane << 3), &Vt[off]);
    }
    __syncthreads();

    f32x4 zero = {0.f, 0.f, 0.f, 0.f};

    for (int chunk = 0; chunk < 4; ++chunk) {
        const int q0 = wave * 64 + chunk * 16;     // query base (residue)
        const bf16x8 qf = *(const bf16x8*)(Qb + base + (size_t)(q0 + li) * 32 + quad * 8);
        const float kmul = (qflag[q0 + li] != 0.0f) ? 0.0f : 1.0f;
        unsigned gpre[4];
        #pragma unroll
        for (int r = 0; r < 4; ++r)
            gpre[r] = *(const unsigned*)(Gb + base +
                          (size_t)(q0 + 4 * quad + r) * 32 + 2 * li);

        f32x4 sc[16];
        __builtin_amdgcn_s_setprio(1);
        #pragma unroll
        for (int t = 0; t < 16; ++t) {
            const int kr = (t >> 1) * 32 + ((li >> 2) << 3) + ((t & 1) << 2) + (li & 3);
            const int sw = (kr & 3) ^ ((kr >> 2) & 3);
            const bf16x8 kf = *(const bf16x8*)&Kl[kr * 32 + ((quad ^ sw) << 3)];
            sc[t] = mfma16(kf, qf, zero);
        }
        __builtin_amdgcn_s_setprio(0);
        // bias + exp2 + sum (exp2 domain; masked -> exp2(-14427) == 0)
        float ls = 0.0f;
        #pragma unroll
        for (int t = 0; t < 16; ++t) {
            const float4 kb4 = ((const float4*)kbias)[(t >> 1) * 8 + quad * 2 + (t & 1)];
            sc[t][0] = exp2f(kmul * kb4.x + sc[t][0]);
            sc[t][1] = exp2f(kmul * kb4.y + sc[t][1]);
            sc[t][2] = exp2f(kmul * kb4.z + sc[t][2]);
            sc[t][3] = exp2f(kmul * kb4.w + sc[t][3]);
            ls += sc[t][0] + sc[t][1] + sc[t][2] + sc[t][3];
        }
        ls += __shfl_xor(ls, 16);
        ls += __shfl_xor(ls, 32);
        const float inv_own = 1.0f / ls;

        f32x4 a0 = zero, a1 = zero;
        __builtin_amdgcn_s_setprio(1);
        #pragma unroll
        for (int kbk = 0; kbk < 8; ++kbk) {
            u32x4 pu;
            pu[0] = cvtpk2(sc[2 * kbk][0],     sc[2 * kbk][1]);
            pu[1] = cvtpk2(sc[2 * kbk][2],     sc[2 * kbk][3]);
            pu[2] = cvtpk2(sc[2 * kbk + 1][0], sc[2 * kbk + 1][1]);
            pu[3] = cvtpk2(sc[2 * kbk + 1][2], sc[2 * kbk + 1][3]);
            const bf16x8 pf = __builtin_bit_cast(bf16x8, pu);
            const int vsw = (4 * kbk + quad) & 7;
            const bf16x8 v0 = *(const bf16x8*)&Vt[kbk * 1024 + quad * 128 + ((li ^ vsw) << 3)];
            const bf16x8 v1 = *(const bf16x8*)&Vt[kbk * 1024 + 512 + quad * 128 + ((li ^ vsw) << 3)];
            a0 = mfma16(pf, v0, a0);
            a1 = mfma16(pf, v1, a1);
        }
        __builtin_amdgcn_s_setprio(0);
        #pragma unroll
        for (int r = 0; r < 4; ++r) {
            const float inv = __shfl(inv_own, 4 * quad + r);
            const int rowq = q0 + 4 * quad + r;
            const size_t ro = base + (size_t)rowq * 32;
            const unsigned gu = gpre[r];
            const float g0 = bf2f((ushort)(gu & 0xFFFFu));
            const float g1 = bf2f((ushort)(gu >> 16));
            const float x0 = a0[r] * inv * g0;
            const float x1 = a1[r] * inv * g1;
            *(unsigned*)&Ohi[ro + 2 * li] = cvtpk2(x0, x1);
        }
    }
}

// ---------------------------------------------------------------------------
// Final GEMM v4 (unchanged): O hi-only -> 2-term product (Ahi x (Whi+Wlo)).
// 3 loads/tile (vmcnt(3)), 48 KB LDS dbuf. 512-thread / 8-wave, M128 x N128.
// ---------------------------------------------------------------------------
__global__ __launch_bounds__(512, 4)
void gemm_mfma(const ushort* __restrict__ Ahi,
               const ushort* __restrict__ Whi, const ushort* __restrict__ Wlo,
               const float* __restrict__ bias, float* __restrict__ outp) {
    __shared__ __align__(16) ushort lds[2][12288];
    const int tid = threadIdx.x;
    const int lane = tid & 63, wave = tid >> 6;
    const int li = lane & 15, quad = lane >> 4;
    const int m0 = blockIdx.y << 7, n0 = blockIdx.x << 7;
    const int wm = (wave >> 2) << 6;        // 0 / 64
    const int wn = (wave & 3) << 5;         // 0 / 32 / 64 / 96
    const int srow = tid >> 2, slot = tid & 3;   // srow in [0,128)
    const int sw0 = (srow & 3) ^ ((srow >> 2) & 3);
    const int gk0 = (slot ^ sw0) << 3;

    f32x4 zero = {0.f, 0.f, 0.f, 0.f};
    f32x4 acc[4][2];
    #pragma unroll
    for (int i = 0; i < 4; ++i)
        #pragma unroll
        for (int j = 0; j < 2; ++j) acc[i][j] = zero;

#define GSTAGE(kt, buf) do {                                                   \
    const size_t hplane_ = (size_t)((kt) >> 5) * HB;                           \
    const size_t ao_ = hplane_ + (size_t)(m0 + srow) * 32 + gk0;               \
    const size_t wo_ = (size_t)(n0 + srow) * 256 + (kt) + gk0;                 \
    gload_lds16(Ahi + ao_, &lds[buf][wave * 512]);                             \
    gload_lds16(Whi + wo_, &lds[buf][4096 + wave * 512]);                      \
    gload_lds16(Wlo + wo_, &lds[buf][8192 + wave * 512]);                      \
    } while (0)

#define GCOMPUTE(buf) do {                                                     \
    bf16x8 ah_[4], bh_[2], bl_[2];                                             \
    _Pragma("unroll")                                                          \
    for (int mt_ = 0; mt_ < 4; ++mt_) {                                        \
        const int r_ = wm + mt_ * 16 + li;                                     \
        const int sw_ = (r_ & 3) ^ ((r_ >> 2) & 3);                            \
        const int off_ = r_ * 32 + ((quad ^ sw_) << 3);                        \
        ah_[mt_] = *(const bf16x8*)&lds[buf][off_];                            \
    }                                                                          \
    _Pragma("unroll")                                                          \
    for (int nt_ = 0; nt_ < 2; ++nt_) {                                        \
        const int r_ = wn + nt_ * 16 + li;                                     \
        const int sw_ = (r_ & 3) ^ ((r_ >> 2) & 3);                            \
        const int off_ = r_ * 32 + ((quad ^ sw_) << 3);                        \
        bh_[nt_] = *(const bf16x8*)&lds[buf][4096 + off_];                     \
        bl_[nt_] = *(const bf16x8*)&lds[buf][8192 + off_];                     \
    }                                                                          \
    _Pragma("unroll")                                                          \
    for (int mt_ = 0; mt_ < 4; ++mt_)                                          \
        _Pragma("unroll")                                                      \
        for (int nt_ = 0; nt_ < 2; ++nt_) {                                    \
            acc[mt_][nt_] = mfma16(ah_[mt_], bh_[nt_], acc[mt_][nt_]);         \
            acc[mt_][nt_] = mfma16(ah_[mt_], bl_[nt_], acc[mt_][nt_]);         \
        } } while (0)

    GSTAGE(0, 0);
    int cur = 0;
    for (int kt = 32; kt < 256; kt += 32) {
        GSTAGE(kt, cur ^ 1);                      // 3 loads in flight
        asm volatile("s_waitcnt vmcnt(3)\n\ts_barrier" ::: "memory");
        GCOMPUTE(cur);
        asm volatile("s_barrier" ::: "memory");
        cur ^= 1;
    }
    asm volatile("s_waitcnt vmcnt(0)\n\ts_barrier" ::: "memory");
    GCOMPUTE(cur);

#undef GSTAGE
#undef GCOMPUTE

    #pragma unroll
    for (int mt = 0; mt < 4; ++mt) {
        const int rowb = m0 + wm + mt * 16 + quad * 4;
        #pragma unroll
        for (int nt = 0; nt < 2; ++nt) {
            const int col = n0 + wn + nt * 16 + li;
            const float bv = bias[col];
            #pragma unroll
            for (int r = 0; r < 4; ++r) {
                const size_t o = (size_t)(rowb + r) * 256 + col;
                outp[o] = acc[mt][nt][r] + bv;
            }
        }
    }
}

// ---------------------------------------------------------------------------
// Launch. Ahi (normalized input, bf16) ALIASES Ohi: dead by the time attn2
// writes Ohi (qkvg consumed A first; stream-ordered).
// ---------------------------------------------------------------------------
extern "C" void kernel_launch(void* const* d_in, const int* in_sizes, int n_in,
                              void* d_out, int out_size, void* d_ws, size_t ws_size,
                              hipStream_t stream) {
    const float* m    = (const float*)d_in[0];
    const unsigned* seqp = (const unsigned*)d_in[1];
    const unsigned* resp = (const unsigned*)d_in[2];
    const float* lng  = (const float*)d_in[3];
    const float* lnb  = (const float*)d_in[4];
    const float* Wq   = (const float*)d_in[5];
    const float* Wk   = (const float*)d_in[6];
    const float* Wv   = (const float*)d_in[7];
    const float* Wg   = (const float*)d_in[8];
    const float* bg   = (const float*)d_in[9];
    const float* Wo   = (const float*)d_in[10];
    const float* bo   = (const float*)d_in[11];
    float* out = (float*)d_out;

    char* p = (char*)d_ws;
    const size_t ABYTES = (size_t)Mrows * Dm * 2;      // 16.78 MB
    ushort* Whi = (ushort*)p;  p += 5 * 65536 * 2;
    ushort* Wlo = (ushort*)p;  p += 5 * 65536 * 2;
    ushort* qb  = (ushort*)p;  p += ABYTES;
    ushort* kb  = (ushort*)p;  p += ABYTES;
    ushort* vb  = (ushort*)p;  p += ABYTES;   // holds V^T planes
    ushort* gbf = (ushort*)p;  p += ABYTES;
    ushort* Ohi = (ushort*)p;  p += ABYTES;
    float* qflag = (float*)p;  p += 1024;
    float* kbias = (float*)p;  p += 1024;

    ushort* Ahi = Ohi;     // alias: dead until attn2 writes Ohi

    prep_all<<<8513, 256, 0, stream>>>(m, lng, lnb, Ahi,
                                       Wq, Wk, Wv, Wg, Wo, Whi, Wlo,
                                       seqp, resp, qflag, kbias);

    // qscale = 1/sqrt(32) * log2(e): softmax computed in exp2 domain.
    const float qscale = 0.17677669529663687f * 1.4426950408889634f;
    qkvg_fused<<<dim3(256, 4), 512, 0, stream>>>(Ahi, Whi, bg,
                                                 qb, kb, vb, gbf, qscale);

    attn2<<<dim3(8, 128), 256, 0, stream>>>(qb, kb, vb, gbf, qflag, kbias, Ohi);

    gemm_mfma<<<dim3(2, 256), 512, 0, stream>>>(Ohi, Whi + 4 * 65536, Wlo + 4 * 65536,
                                                bo, out);
}

// Round 15
// 170.392 us; speedup vs baseline: 1.1721x; 1.0628x over previous
//
#include <hip/hip_runtime.h>
#include <math.h>

#define NEG_INF -10000.0f
// NEG_INF * log2(e): masked scores live in exp2 domain now
#define NEG_INF_L2E -14426.950408889634f

typedef short bf16x8 __attribute__((ext_vector_type(8)));
typedef float f32x4 __attribute__((ext_vector_type(4)));
typedef unsigned u32x4 __attribute__((ext_vector_type(4)));

static constexpr int Dm = 256;   // model dim
static constexpr int Lm = 256;   // residues
static constexpr int Sm = 128;   // sequences
static constexpr int Mrows = Sm * Lm;  // 32768
static constexpr size_t HB = (size_t)Mrows * 32;  // head-plane stride (elems)

__device__ __forceinline__ ushort f2bf(float x) {
    unsigned u = __float_as_uint(x);
    unsigned r = (u + 0x7FFFu + ((u >> 16) & 1u)) >> 16;
    return (ushort)r;
}
__device__ __forceinline__ float bf2f(ushort h) {
    return __uint_as_float(((unsigned)h) << 16);
}
// packed f32x2 -> bf16x2 (RNE; bit-identical to f2bf for normals)
__device__ __forceinline__ unsigned cvtpk2(float a, float b) {
    unsigned r;
    asm("v_cvt_pk_bf16_f32 %0, %1, %2" : "=v"(r) : "v"(a), "v"(b));
    return r;
}
__device__ __forceinline__ void gload_lds16(const void* g, void* l) {
    __builtin_amdgcn_global_load_lds((__attribute__((address_space(1))) void*)g,
                                     (__attribute__((address_space(3))) void*)l,
                                     16, 0, 0);
}
__device__ __forceinline__ f32x4 mfma16(bf16x8 a, bf16x8 b, f32x4 c) {
    return __builtin_amdgcn_mfma_f32_16x16x32_bf16(a, b, c, 0, 0, 0);
}

// ---------------------------------------------------------------------------
// prep_all: one launch for LN (blocks [0,8192)), W bf16 split
// (blocks [8192,8512): 5 mats x 64, HI ONLY now), mask decode (block 8512).
// ---------------------------------------------------------------------------
__global__ __launch_bounds__(256)
void prep_all(const float* __restrict__ m, const float* __restrict__ lng,
              const float* __restrict__ lnb,
              ushort* __restrict__ Ahi,
              const float* __restrict__ W0, const float* __restrict__ W1,
              const float* __restrict__ W2, const float* __restrict__ W3,
              const float* __restrict__ W4, ushort* __restrict__ Whi,
              const unsigned* __restrict__ seq_raw,
              const unsigned* __restrict__ res_raw,
              float* __restrict__ qflag, float* __restrict__ kbias) {
    const int bx = blockIdx.x;
    if (bx < 8192) {
        // ---- LayerNorm + bf16 (hi only): one wave per row ----
        const int wid = threadIdx.x >> 6, lane = threadIdx.x & 63;
        const int row = (bx << 2) + wid;
        const float4 a = ((const float4*)(m + (size_t)row * Dm))[lane];
        float s  = a.x + a.y + a.z + a.w;
        float ss = a.x*a.x + a.y*a.y + a.z*a.z + a.w*a.w;
        #pragma unroll
        for (int off = 32; off > 0; off >>= 1) {
            s  += __shfl_xor(s, off);
            ss += __shfl_xor(ss, off);
        }
        const float mu = s * (1.0f / 256.0f);
        const float rs = rsqrtf(ss * (1.0f / 256.0f) - mu * mu + 1e-5f);
        const float4 g = ((const float4*)lng)[lane];
        const float4 b = ((const float4*)lnb)[lane];
        const float x0 = (a.x - mu) * rs * g.x + b.x;
        const float x1 = (a.y - mu) * rs * g.y + b.y;
        const float x2 = (a.z - mu) * rs * g.z + b.z;
        const float x3 = (a.w - mu) * rs * g.w + b.w;
        uint2 hv;
        hv.x = cvtpk2(x0, x1);
        hv.y = cvtpk2(x2, x3);
        const size_t o = (size_t)row * 256 + 4 * lane;
        *(uint2*)(Ahi + o) = hv;
        return;
    }
    if (bx < 8512) {
        // ---- W bf16 (hi only), mats 0-3 even/odd row-permuted ----
        const int b = bx - 8192;
        const int mat = b >> 6, xb = b & 63;
        const float* Ws[5] = {W0, W1, W2, W3, W4};
        const size_t idx = ((size_t)xb * 256 + threadIdx.x) * 4;
        const float4 v = *(const float4*)(Ws[mat] + idx);
        ushort4 hi;
        hi.x = f2bf(v.x);
        hi.y = f2bf(v.y);
        hi.z = f2bf(v.z);
        hi.w = f2bf(v.w);
        const int row = (int)(idx >> 8), col = (int)(idx & 255);
        int drow = row;
        if (mat < 4) {
            const int ch = row & 31;
            const int p = (ch & 1) ? 16 + (ch >> 1) : (ch >> 1);
            drow = (row & ~31) | p;
        }
        const size_t o = (size_t)mat * 65536 + (size_t)drow * 256 + col;
        *(ushort4*)(Whi + o) = hi;
        return;
    }
    // ---- mask decode (single block) ----
    __shared__ unsigned long long sb[4], sf[4];
    __shared__ int enc;
    const int t = threadIdx.x;
    unsigned w = 0;
    if (t < 64)        w = seq_raw[t];
    else if (t < 128)  w = res_raw[t - 64];
    bool bad = (w != 0u) && (w != 1u) && (w != 0x3f800000u);
    bool isf = (w == 0x3f800000u);
    unsigned long long bm = __ballot(bad);
    unsigned long long fm = __ballot(isf);
    const int wid = t >> 6;
    if ((t & 63) == 0) { sb[wid] = bm; sf[wid] = fm; }
    __syncthreads();
    if (t == 0) {
        unsigned long long B = sb[0] | sb[1];
        unsigned long long F = sf[0] | sf[1];
        enc = B ? 2 : (F ? 1 : 0);
    }
    __syncthreads();
    const int e = enc;
    int sv, rv;
    if (e == 2) {
        const unsigned char* sp = (const unsigned char*)seq_raw;
        const unsigned char* rp = (const unsigned char*)res_raw;
        sv = sp[t]; rv = rp[t];
    } else if (e == 1) {
        sv = (((const float*)seq_raw)[t] != 0.0f);
        rv = (((const float*)res_raw)[t] != 0.0f);
    } else {
        sv = (seq_raw[t] != 0u);
        rv = (res_raw[t] != 0u);
    }
    qflag[t] = sv ? NEG_INF : 0.0f;
    kbias[t] = rv ? NEG_INF_L2E : 0.0f;   // pre-scaled for exp2-domain softmax
}

// ---------------------------------------------------------------------------
// Fused QKVG GEMM v8 (frozen): A HI-ONLY single-term product. 3 loads/tile
// (vmcnt(3)), 48 KB LDS dbuf. 512-thread, M=128 x N=256, per-wave 64x64.
// V (mat==2) stored PRE-TRANSPOSED in attn2's swizzled V^T plane layout.
// qscale includes log2(e).
// ---------------------------------------------------------------------------
__global__ __launch_bounds__(512, 4)
void qkvg_fused(const ushort* __restrict__ Ahig,
                const ushort* __restrict__ Whi, const float* __restrict__ bg,
                ushort* __restrict__ qb, ushort* __restrict__ kb,
                ushort* __restrict__ vb, ushort* __restrict__ gbf,
                float qscale) {
    __shared__ __align__(16) ushort Wh[2][256 * 32];   // 2 x 16 KB
    __shared__ __align__(16) ushort Ah[2][128 * 32];   // 2 x 8 KB
    const int tid = threadIdx.x, lane = tid & 63, wave = tid >> 6;
    const int li = lane & 15, quad = lane >> 4;
    const int m0 = blockIdx.x << 7;         // m-tile (fastest), M=128
    const int mat = blockIdx.y;             // matrix 0..3
    const int wm = (wave >> 2) << 6;        // wave m-half: 0 / 64
    const int wn = (wave & 3) << 6;         // wave n-slice: 0/64/128/192

    const int l4 = lane >> 2, slot = lane & 3;

    f32x4 zero = {0.f, 0.f, 0.f, 0.f};
    f32x4 acc[4][4];
    #pragma unroll
    for (int i = 0; i < 4; ++i)
        #pragma unroll
        for (int j = 0; j < 4; ++j) acc[i][j] = zero;

    const ushort* Wmat = Whi + (size_t)mat * 65536;

#define STAGE(kt, buf) do {                                                    \
    _Pragma("unroll")                                                          \
    for (int j_ = 0; j_ < 2; ++j_) {                                           \
        const int wrow_ = wave * 32 + j_ * 16 + l4;                            \
        const int wsw_ = (wrow_ & 3) ^ ((wrow_ >> 2) & 3);                     \
        gload_lds16(Wmat + (size_t)wrow_ * 256 + (kt) + ((slot ^ wsw_) << 3),  \
                    &Wh[buf][wave * 1024 + j_ * 512]);                         \
    }                                                                          \
    {                                                                          \
        const int arow_ = wave * 16 + l4;                                      \
        const int asw_ = (arow_ & 3) ^ ((arow_ >> 2) & 3);                     \
        const size_t asrc_ = (size_t)(m0 + arow_) * 256 + (kt) + ((slot ^ asw_) << 3); \
        gload_lds16(Ahig + asrc_, &Ah[buf][wave * 512]);                       \
    } } while (0)

#define COMPUTE(buf) do {                                                      \
    bf16x8 ah_[4];                                                             \
    _Pragma("unroll")                                                          \
    for (int mt_ = 0; mt_ < 4; ++mt_) {                                        \
        const int r_ = wm + mt_ * 16 + li;                                     \
        const int sw_ = (r_ & 3) ^ ((r_ >> 2) & 3);                            \
        const int off_ = r_ * 32 + ((quad ^ sw_) << 3);                        \
        ah_[mt_] = *(const bf16x8*)&Ah[buf][off_];                             \
    }                                                                          \
    _Pragma("unroll")                                                          \
    for (int nt_ = 0; nt_ < 4; ++nt_) {                                        \
        const int rn_ = wn + nt_ * 16 + li;                                    \
        const int sw_ = (rn_ & 3) ^ ((rn_ >> 2) & 3);                          \
        const bf16x8 bh_ = *(const bf16x8*)&Wh[buf][rn_ * 32 + ((quad ^ sw_) << 3)]; \
        _Pragma("unroll")                                                      \
        for (int mt_ = 0; mt_ < 4; ++mt_) {                                    \
            acc[mt_][nt_] = mfma16(ah_[mt_], bh_, acc[mt_][nt_]);              \
        }                                                                      \
    } } while (0)

    STAGE(0, 0);
    int cur = 0;
    for (int kt = 32; kt < 256; kt += 32) {
        STAGE(kt, cur ^ 1);                       // 3 loads -> in flight
        asm volatile("s_waitcnt vmcnt(3)\n\ts_barrier" ::: "memory");
        COMPUTE(cur);
        asm volatile("s_barrier" ::: "memory");   // readers done before overwrite
        cur ^= 1;
    }
    asm volatile("s_waitcnt vmcnt(0)\n\ts_barrier" ::: "memory");
    COMPUTE(cur);                                 // last tile

#undef STAGE
#undef COMPUTE

    if (mat == 2) {
        // V epilogue: store into attn2's swizzled V^T plane layout.
        const int s = m0 >> 8;                    // sequence of this 128-row tile
        const int keyOff = m0 & 255;              // 0 or 128 within the plane
        #pragma unroll
        for (int j = 0; j < 2; ++j) {
            const int hh = (wave & 3) * 2 + j;
            #pragma unroll
            for (int mt = 0; mt < 4; ++mt) {
                const int key = keyOff + wm + mt * 16 + quad * 4;  // r=0 key
                const int vkb = key >> 5, vq = (key >> 3) & 3, vj0 = key & 7;
                const int vsw = (4 * vkb + vq) & 7;
                const size_t pb = (size_t)hh * HB + (size_t)s * 8192
                                + vkb * 1024 + vq * 128 + ((li ^ vsw) << 3) + vj0;
                uint2 uE, uO;
                uE.x = cvtpk2(acc[mt][2 * j][0],     acc[mt][2 * j][1]);
                uE.y = cvtpk2(acc[mt][2 * j][2],     acc[mt][2 * j][3]);
                uO.x = cvtpk2(acc[mt][2 * j + 1][0], acc[mt][2 * j + 1][1]);
                uO.y = cvtpk2(acc[mt][2 * j + 1][2], acc[mt][2 * j + 1][3]);
                *(uint2*)&vb[pb]       = uE;
                *(uint2*)&vb[pb + 512] = uO;
            }
        }
    } else {
        ushort* outp = (mat == 0) ? qb : (mat == 1) ? kb : gbf;
        #pragma unroll
        for (int j = 0; j < 2; ++j) {
            const int hh = (wave & 3) * 2 + j;
            const int cE = hh * 32 + 2 * li;
            const float2 bg2 = *(const float2*)(bg + cE);
            #pragma unroll
            for (int mt = 0; mt < 4; ++mt) {
                #pragma unroll
                for (int r = 0; r < 4; ++r) {
                    const int row = m0 + wm + mt * 16 + quad * 4 + r;
                    float vE = acc[mt][2 * j][r];
                    float vO = acc[mt][2 * j + 1][r];
                    if (mat == 0) { vE *= qscale; vO *= qscale; }
                    if (mat == 3) {
                        vE = 1.0f / (1.0f + __expf(-(vE + bg2.x)));
                        vO = 1.0f / (1.0f + __expf(-(vO + bg2.y)));
                    }
                    const unsigned u = cvtpk2(vE, vO);
                    *(unsigned*)&outp[(size_t)hh * HB + (size_t)row * 32 + 2 * li] = u;
                }
            }
        }
    }
}

// ---------------------------------------------------------------------------
// Attention v10 (frozen): O hi-only, exp2-domain softmax, no max pass,
// V pre-transposed; Q/G direct from global.
// ---------------------------------------------------------------------------
__global__ __launch_bounds__(256, 2)
void attn2(const ushort* __restrict__ Qb, const ushort* __restrict__ Kb,
           const ushort* __restrict__ Vtb, const ushort* __restrict__ Gb,
           const float* __restrict__ qflag, const float* __restrict__ kbias,
           ushort* __restrict__ Ohi) {
    __shared__ __align__(16) ushort Kl[8192];   // 16 KB swizzled K
    __shared__ __align__(16) ushort Vt[8192];   // 16 KB paired/swizzled V^T
    const int h = blockIdx.x, s = blockIdx.y;
    const int tid = threadIdx.x, lane = tid & 63, wave = tid >> 6;
    const int li = lane & 15, quad = lane >> 4;
    const size_t base = (size_t)h * HB + (size_t)s * 8192;

    // --- K staging (XOR-swizzled, global_load_lds) ---
    const int srow = tid >> 2, slot = tid & 3;
    const int sw0 = (srow & 3) ^ ((srow >> 2) & 3);
    const int gk0 = (slot ^ sw0) << 3;
    #pragma unroll
    for (int i = 0; i < 4; ++i) {
        const int r = i * 64 + srow;
        gload_lds16(Kb + base + (size_t)r * 32 + gk0, &Kl[i * 2048 + wave * 512]);
    }
    // --- V^T staging: linear copy (layout pre-arranged by qkvg) ---
    #pragma unroll
    for (int i = 0; i < 4; ++i) {
        const int off = i * 2048 + wave * 512;
        gload_lds16(Vtb + base + off + (lane << 3), &Vt[off]);
    }
    __syncthreads();

    f32x4 zero = {0.f, 0.f, 0.f, 0.f};

    for (int chunk = 0; chunk < 4; ++chunk) {
        const int q0 = wave * 64 + chunk * 16;     // query base (residue)
        const bf16x8 qf = *(const bf16x8*)(Qb + base + (size_t)(q0 + li) * 32 + quad * 8);
        const float kmul = (qflag[q0 + li] != 0.0f) ? 0.0f : 1.0f;
        unsigned gpre[4];
        #pragma unroll
        for (int r = 0; r < 4; ++r)
            gpre[r] = *(const unsigned*)(Gb + base +
                          (size_t)(q0 + 4 * quad + r) * 32 + 2 * li);

        f32x4 sc[16];
        __builtin_amdgcn_s_setprio(1);
        #pragma unroll
        for (int t = 0; t < 16; ++t) {
            const int kr = (t >> 1) * 32 + ((li >> 2) << 3) + ((t & 1) << 2) + (li & 3);
            const int sw = (kr & 3) ^ ((kr >> 2) & 3);
            const bf16x8 kf = *(const bf16x8*)&Kl[kr * 32 + ((quad ^ sw) << 3)];
            sc[t] = mfma16(kf, qf, zero);
        }
        __builtin_amdgcn_s_setprio(0);
        // bias + exp2 + sum (exp2 domain; masked -> exp2(-14427) == 0)
        float ls = 0.0f;
        #pragma unroll
        for (int t = 0; t < 16; ++t) {
            const float4 kb4 = ((const float4*)kbias)[(t >> 1) * 8 + quad * 2 + (t & 1)];
            sc[t][0] = exp2f(kmul * kb4.x + sc[t][0]);
            sc[t][1] = exp2f(kmul * kb4.y + sc[t][1]);
            sc[t][2] = exp2f(kmul * kb4.z + sc[t][2]);
            sc[t][3] = exp2f(kmul * kb4.w + sc[t][3]);
            ls += sc[t][0] + sc[t][1] + sc[t][2] + sc[t][3];
        }
        ls += __shfl_xor(ls, 16);
        ls += __shfl_xor(ls, 32);
        const float inv_own = 1.0f / ls;

        f32x4 a0 = zero, a1 = zero;
        __builtin_amdgcn_s_setprio(1);
        #pragma unroll
        for (int kbk = 0; kbk < 8; ++kbk) {
            u32x4 pu;
            pu[0] = cvtpk2(sc[2 * kbk][0],     sc[2 * kbk][1]);
            pu[1] = cvtpk2(sc[2 * kbk][2],     sc[2 * kbk][3]);
            pu[2] = cvtpk2(sc[2 * kbk + 1][0], sc[2 * kbk + 1][1]);
            pu[3] = cvtpk2(sc[2 * kbk + 1][2], sc[2 * kbk + 1][3]);
            const bf16x8 pf = __builtin_bit_cast(bf16x8, pu);
            const int vsw = (4 * kbk + quad) & 7;
            const bf16x8 v0 = *(const bf16x8*)&Vt[kbk * 1024 + quad * 128 + ((li ^ vsw) << 3)];
            const bf16x8 v1 = *(const bf16x8*)&Vt[kbk * 1024 + 512 + quad * 128 + ((li ^ vsw) << 3)];
            a0 = mfma16(pf, v0, a0);
            a1 = mfma16(pf, v1, a1);
        }
        __builtin_amdgcn_s_setprio(0);
        #pragma unroll
        for (int r = 0; r < 4; ++r) {
            const float inv = __shfl(inv_own, 4 * quad + r);
            const int rowq = q0 + 4 * quad + r;
            const size_t ro = base + (size_t)rowq * 32;
            const unsigned gu = gpre[r];
            const float g0 = bf2f((ushort)(gu & 0xFFFFu));
            const float g1 = bf2f((ushort)(gu >> 16));
            const float x0 = a0[r] * inv * g0;
            const float x1 = a1[r] * inv * g1;
            *(unsigned*)&Ohi[ro + 2 * li] = cvtpk2(x0, x1);
        }
    }
}

// ---------------------------------------------------------------------------
// Final GEMM v5: single-term product (Ahi x Whi), Wlo retired. 2 loads/tile
// (vmcnt(2)), 32 KB LDS dbuf. 512-thread / 8-wave, M128 x N128, per-wave
// 64x32, counted-vmcnt pipeline, fp32 out + bias.
// ---------------------------------------------------------------------------
__global__ __launch_bounds__(512, 4)
void gemm_mfma(const ushort* __restrict__ Ahi,
               const ushort* __restrict__ Whi,
               const float* __restrict__ bias, float* __restrict__ outp) {
    __shared__ __align__(16) ushort lds[2][8192];
    const int tid = threadIdx.x;
    const int lane = tid & 63, wave = tid >> 6;
    const int li = lane & 15, quad = lane >> 4;
    const int m0 = blockIdx.y << 7, n0 = blockIdx.x << 7;
    const int wm = (wave >> 2) << 6;        // 0 / 64
    const int wn = (wave & 3) << 5;         // 0 / 32 / 64 / 96
    const int srow = tid >> 2, slot = tid & 3;   // srow in [0,128)
    const int sw0 = (srow & 3) ^ ((srow >> 2) & 3);
    const int gk0 = (slot ^ sw0) << 3;

    f32x4 zero = {0.f, 0.f, 0.f, 0.f};
    f32x4 acc[4][2];
    #pragma unroll
    for (int i = 0; i < 4; ++i)
        #pragma unroll
        for (int j = 0; j < 2; ++j) acc[i][j] = zero;

#define GSTAGE(kt, buf) do {                                                   \
    const size_t hplane_ = (size_t)((kt) >> 5) * HB;                           \
    const size_t ao_ = hplane_ + (size_t)(m0 + srow) * 32 + gk0;               \
    const size_t wo_ = (size_t)(n0 + srow) * 256 + (kt) + gk0;                 \
    gload_lds16(Ahi + ao_, &lds[buf][wave * 512]);                             \
    gload_lds16(Whi + wo_, &lds[buf][4096 + wave * 512]);                      \
    } while (0)

#define GCOMPUTE(buf) do {                                                     \
    bf16x8 ah_[4], bh_[2];                                                     \
    _Pragma("unroll")                                                          \
    for (int mt_ = 0; mt_ < 4; ++mt_) {                                        \
        const int r_ = wm + mt_ * 16 + li;                                     \
        const int sw_ = (r_ & 3) ^ ((r_ >> 2) & 3);                            \
        const int off_ = r_ * 32 + ((quad ^ sw_) << 3);                        \
        ah_[mt_] = *(const bf16x8*)&lds[buf][off_];                            \
    }                                                                          \
    _Pragma("unroll")                                                          \
    for (int nt_ = 0; nt_ < 2; ++nt_) {                                        \
        const int r_ = wn + nt_ * 16 + li;                                     \
        const int sw_ = (r_ & 3) ^ ((r_ >> 2) & 3);                            \
        const int off_ = r_ * 32 + ((quad ^ sw_) << 3);                        \
        bh_[nt_] = *(const bf16x8*)&lds[buf][4096 + off_];                     \
    }                                                                          \
    _Pragma("unroll")                                                          \
    for (int mt_ = 0; mt_ < 4; ++mt_)                                          \
        _Pragma("unroll")                                                      \
        for (int nt_ = 0; nt_ < 2; ++nt_) {                                    \
            acc[mt_][nt_] = mfma16(ah_[mt_], bh_[nt_], acc[mt_][nt_]);         \
        } } while (0)

    GSTAGE(0, 0);
    int cur = 0;
    for (int kt = 32; kt < 256; kt += 32) {
        GSTAGE(kt, cur ^ 1);                      // 2 loads in flight
        asm volatile("s_waitcnt vmcnt(2)\n\ts_barrier" ::: "memory");
        GCOMPUTE(cur);
        asm volatile("s_barrier" ::: "memory");
        cur ^= 1;
    }
    asm volatile("s_waitcnt vmcnt(0)\n\ts_barrier" ::: "memory");
    GCOMPUTE(cur);

#undef GSTAGE
#undef GCOMPUTE

    #pragma unroll
    for (int mt = 0; mt < 4; ++mt) {
        const int rowb = m0 + wm + mt * 16 + quad * 4;
        #pragma unroll
        for (int nt = 0; nt < 2; ++nt) {
            const int col = n0 + wn + nt * 16 + li;
            const float bv = bias[col];
            #pragma unroll
            for (int r = 0; r < 4; ++r) {
                const size_t o = (size_t)(rowb + r) * 256 + col;
                outp[o] = acc[mt][nt][r] + bv;
            }
        }
    }
}

// ---------------------------------------------------------------------------
// Launch. Ahi (normalized input, bf16) ALIASES Ohi: dead by the time attn2
// writes Ohi (qkvg consumed A first; stream-ordered).
// ---------------------------------------------------------------------------
extern "C" void kernel_launch(void* const* d_in, const int* in_sizes, int n_in,
                              void* d_out, int out_size, void* d_ws, size_t ws_size,
                              hipStream_t stream) {
    const float* m    = (const float*)d_in[0];
    const unsigned* seqp = (const unsigned*)d_in[1];
    const unsigned* resp = (const unsigned*)d_in[2];
    const float* lng  = (const float*)d_in[3];
    const float* lnb  = (const float*)d_in[4];
    const float* Wq   = (const float*)d_in[5];
    const float* Wk   = (const float*)d_in[6];
    const float* Wv   = (const float*)d_in[7];
    const float* Wg   = (const float*)d_in[8];
    const float* bg   = (const float*)d_in[9];
    const float* Wo   = (const float*)d_in[10];
    const float* bo   = (const float*)d_in[11];
    float* out = (float*)d_out;

    char* p = (char*)d_ws;
    const size_t ABYTES = (size_t)Mrows * Dm * 2;      // 16.78 MB
    ushort* Whi = (ushort*)p;  p += 5 * 65536 * 2;
    ushort* qb  = (ushort*)p;  p += ABYTES;
    ushort* kb  = (ushort*)p;  p += ABYTES;
    ushort* vb  = (ushort*)p;  p += ABYTES;   // holds V^T planes
    ushort* gbf = (ushort*)p;  p += ABYTES;
    ushort* Ohi = (ushort*)p;  p += ABYTES;
    float* qflag = (float*)p;  p += 1024;
    float* kbias = (float*)p;  p += 1024;

    ushort* Ahi = Ohi;     // alias: dead until attn2 writes Ohi

    prep_all<<<8513, 256, 0, stream>>>(m, lng, lnb, Ahi,
                                       Wq, Wk, Wv, Wg, Wo, Whi,
                                       seqp, resp, qflag, kbias);

    // qscale = 1/sqrt(32) * log2(e): softmax computed in exp2 domain.
    const float qscale = 0.17677669529663687f * 1.4426950408889634f;
    qkvg_fused<<<dim3(256, 4), 512, 0, stream>>>(Ahi, Whi, bg,
                                                 qb, kb, vb, gbf, qscale);

    attn2<<<dim3(8, 128), 256, 0, stream>>>(qb, kb, vb, gbf, qflag, kbias, Ohi);

    gemm_mfma<<<dim3(2, 256), 512, 0, stream>>>(Ohi, Whi + 4 * 65536,
                                                bo, out);
}